// Round 5
// baseline (508.121 us; speedup 1.0000x reference)
//
#include <hip/hip_runtime.h>
#include <cstdint>
#include <cstddef>

// ---------------- problem constants ----------------
#define NN 50000
#define EE 1600000
#define IN_DIM 256
#define HC 128      // HEADS*C
#define CD 32       // C
#define BN_RS 0.9999950000374997f  // 1/sqrt(1+1e-5)

#define CAP1 128
#define CAP2 128
#define CSTR 32     // counter padding stride (ints): one counter per 128B sector

// ---------------- small helpers ----------------
__device__ __forceinline__ float lrelu(float a) { return a > 0.f ? a : 0.2f * a; }
__device__ __forceinline__ float elu(float a) { return a > 0.f ? a : (__expf(a) - 1.f); }

// bf16 (stored as ushort bits) <-> f32
__device__ __forceinline__ unsigned short f2bf(float f) {
    unsigned int u = __float_as_uint(f);
    unsigned int r = (u + 0x7FFFu + ((u >> 16) & 1u)) >> 16;
    return (unsigned short)r;
}
__device__ __forceinline__ float2 bf2f2(unsigned int p) {
    float2 r;
    r.x = __uint_as_float(p << 16);
    r.y = __uint_as_float(p & 0xFFFF0000u);
    return r;
}
__device__ __forceinline__ void unpack_edge(unsigned long long p, int& s, float& eav) {
    s = (int)(unsigned int)(p & 0xFFFFFFFFull);
    eav = __uint_as_float((unsigned int)(p >> 32));
}

// ---------------- count (8 edges/thread) + rank capture + fused ea-sum ----------------
// counts padded to one counter per 128B sector: same-line atomic serialization
// at the coherence point drops from 512-deep to 32-deep.
__global__ __launch_bounds__(256) void count_kernel(const int* __restrict__ ei,
                                                    const float* __restrict__ ea,
                                                    int* __restrict__ counts,
                                                    int* __restrict__ rank,
                                                    float* __restrict__ easum) {
    int base = blockIdx.x * 2048 + threadIdx.x;
    float s = 0.f;
    #pragma unroll
    for (int k = 0; k < 8; k++) {
        int i = base + k * 256;
        if (i < EE) {
            int r = atomicAdd(&counts[(size_t)ei[EE + i] * CSTR], 1);
            rank[i] = r;
            s += ea[i];
        }
    }
    #pragma unroll
    for (int off = 32; off > 0; off >>= 1) s += __shfl_xor(s, off);
    if ((threadIdx.x & 63) == 0) atomicAdd(easum, s);
}

// ---------------- hierarchical scan (3 tiny kernels) ----------------
__global__ __launch_bounds__(256) void scan_local(const int* __restrict__ counts,
                                                  int* __restrict__ localbuf,
                                                  int* __restrict__ partials, int n) {
    __shared__ int wsum[4];
    int tid = threadIdx.x, lane = tid & 63, wv = tid >> 6;
    int i = blockIdx.x * 1024 + tid * 4;
    int v0 = 0, v1 = 0, v2 = 0, v3 = 0;
    if (i + 0 < n) v0 = counts[(size_t)(i + 0) * CSTR];
    if (i + 1 < n) v1 = counts[(size_t)(i + 1) * CSTR];
    if (i + 2 < n) v2 = counts[(size_t)(i + 2) * CSTR];
    if (i + 3 < n) v3 = counts[(size_t)(i + 3) * CSTR];
    int t = v0 + v1 + v2 + v3;
    int x = t;
    #pragma unroll
    for (int off = 1; off < 64; off <<= 1) {
        int y = __shfl_up(x, off);
        if (lane >= off) x += y;
    }
    if (lane == 63) wsum[wv] = x;
    __syncthreads();
    int wpre = 0;
    #pragma unroll
    for (int w = 0; w < 4; w++)
        if (w < wv) wpre += wsum[w];
    if (i < n) {
        int e0 = wpre + x - t;
        int4 o;
        o.x = e0; o.y = e0 + v0; o.z = o.y + v1; o.w = o.z + v2;
        *(int4*)(localbuf + i) = o;
    }
    if (tid == 0) partials[blockIdx.x] = wsum[0] + wsum[1] + wsum[2] + wsum[3];
}

__global__ void scan_part(int* __restrict__ partials, int* __restrict__ indptr, int nblk) {
    int lane = threadIdx.x;  // 64 threads
    int v = (lane < nblk) ? partials[lane] : 0;
    int x = v;
    #pragma unroll
    for (int off = 1; off < 64; off <<= 1) {
        int y = __shfl_up(x, off);
        if (lane >= off) x += y;
    }
    if (lane < nblk) partials[lane] = x - v;
    if (lane == 0) indptr[NN] = EE;
}

__global__ __launch_bounds__(256) void scan_add(const int* __restrict__ localbuf,
                                                const int* __restrict__ partials,
                                                int* __restrict__ indptr, int n) {
    int i = blockIdx.x * 1024 + threadIdx.x * 4;
    if (i < n) {
        int off = partials[blockIdx.x];
        int4 t = *(const int4*)(localbuf + i);
        t.x += off; t.y += off; t.z += off; t.w += off;
        *(int4*)(indptr + i) = t;
    }
}

// ---------------- scatter: atomic-free, pos = indptr[dst] + rank[e] ----------------
__global__ __launch_bounds__(256) void scatter_kernel(const int* __restrict__ ei,
                                                      const float* __restrict__ ea,
                                                      const int* __restrict__ rank,
                                                      const int* __restrict__ indptr,
                                                      unsigned long long* __restrict__ edgedat) {
    int base = blockIdx.x * 2048 + threadIdx.x;
    #pragma unroll
    for (int k = 0; k < 8; k++) {
        int i = base + k * 256;
        if (i < EE) {
            int src = ei[i];
            int d = ei[EE + i];
            float eav = ea[i];
            int pos = indptr[d] + rank[i];
            edgedat[pos] = (unsigned long long)(unsigned int)src |
                           ((unsigned long long)__float_as_uint(eav) << 32);
        }
    }
}

// ---------------- per-head attention constants + ea mean ----------------
__global__ void prep_kernel(const float* __restrict__ We1, const float* __restrict__ ae1,
                            const float* __restrict__ We2, const float* __restrict__ ae2,
                            float* __restrict__ consts) {
    int lane = threadIdx.x;
    if (lane < 4) {
        float s = 0.f;
        for (int c = 0; c < 32; c++) s += We1[lane * 32 + c] * ae1[lane * 32 + c];
        consts[2 + lane] = s;
    } else if (lane == 4) {
        float s = 0.f;
        for (int c = 0; c < 32; c++) s += We2[c] * ae2[c];
        consts[6] = s;
    } else if (lane == 5) {
        consts[1] = consts[0] / (float)EE;
    }
}

// ---------------- fp32 tiled GEMM: C[M,TN] = A[M,K] @ B[K,TN], bf16 or f32 out ----------------
template <int TM, int TN, int TK, int RM, int RN, bool BF16OUT>
__global__ __launch_bounds__(256) void gemm_kernel(const float* __restrict__ A,
                                                   const float* __restrict__ B,
                                                   void* __restrict__ Cv, int M, int K) {
    static_assert(TM * TN == 256 * RM * RN, "thread coverage");
    static_assert(RN % 2 == 0, "pairable");
    __shared__ float As[TK][TM + 4];
    __shared__ float Bs[TK][TN];
    int tid = threadIdx.x;
    int tx = tid % (TN / RN);
    int ty = tid / (TN / RN);
    int blockRow = blockIdx.x * TM;
    float acc[RM][RN];
    #pragma unroll
    for (int i = 0; i < RM; i++)
        #pragma unroll
        for (int j = 0; j < RN; j++) acc[i][j] = 0.f;

    for (int k0 = 0; k0 < K; k0 += TK) {
        #pragma unroll
        for (int l = 0; l < TM * TK; l += 256 * 4) {
            int ll = l + tid * 4;
            if (ll < TM * TK) {
                int r = ll / TK, kk = ll % TK;
                float4 v = make_float4(0.f, 0.f, 0.f, 0.f);
                int gr = blockRow + r;
                if (gr < M) v = *(const float4*)(A + (size_t)gr * K + k0 + kk);
                As[kk + 0][r] = v.x;
                As[kk + 1][r] = v.y;
                As[kk + 2][r] = v.z;
                As[kk + 3][r] = v.w;
            }
        }
        #pragma unroll
        for (int l = 0; l < TK * TN; l += 256 * 4) {
            int ll = l + tid * 4;
            if (ll < TK * TN) {
                int kk = ll / TN, c = ll % TN;
                *(float4*)&Bs[kk][c] = *(const float4*)(B + (size_t)(k0 + kk) * TN + c);
            }
        }
        __syncthreads();
        #pragma unroll
        for (int k = 0; k < TK; k++) {
            float af[RM], bf[RN];
            #pragma unroll
            for (int i = 0; i < RM; i++) af[i] = As[k][ty * RM + i];
            #pragma unroll
            for (int j = 0; j < RN; j++) bf[j] = Bs[k][tx * RN + j];
            #pragma unroll
            for (int i = 0; i < RM; i++)
                #pragma unroll
                for (int j = 0; j < RN; j++) acc[i][j] += af[i] * bf[j];
        }
        __syncthreads();
    }
    #pragma unroll
    for (int i = 0; i < RM; i++) {
        int gr = blockRow + ty * RM + i;
        if (gr < M) {
            if (BF16OUT) {
                unsigned short* C = (unsigned short*)Cv;
                #pragma unroll
                for (int j = 0; j < RN; j += 2) {
                    unsigned int pk = (unsigned int)f2bf(acc[i][j]) |
                                      ((unsigned int)f2bf(acc[i][j + 1]) << 16);
                    *(unsigned int*)(C + (size_t)gr * TN + tx * RN + j) = pk;
                }
            } else {
                float* C = (float*)Cv;
                #pragma unroll
                for (int j = 0; j < RN; j++) C[(size_t)gr * TN + tx * RN + j] = acc[i][j];
            }
        }
    }
}

// ---------------- attention logits per node (bf16 inputs) ----------------
__global__ void al1_kernel(const unsigned short* __restrict__ xs1b, const float* __restrict__ as1,
                           const float* __restrict__ ad1, float* __restrict__ als,
                           float* __restrict__ ald) {
    int t = blockIdx.x * 256 + threadIdx.x;
    if (t >= NN * 4) return;
    int h = t & 3;
    const unsigned int* xp = (const unsigned int*)(xs1b + (size_t)t * 32);
    const float* ap = as1 + h * 32;
    const float* dp = ad1 + h * 32;
    float s = 0.f, d = 0.f;
    #pragma unroll
    for (int q = 0; q < 16; q++) {
        float2 v = bf2f2(xp[q]);
        s += v.x * ap[q * 2] + v.y * ap[q * 2 + 1];
        d += v.x * dp[q * 2] + v.y * dp[q * 2 + 1];
    }
    als[t] = s;
    ald[t] = d;
}

__global__ void al2_kernel(const unsigned short* __restrict__ xs2b, const float* __restrict__ as2,
                           const float* __restrict__ ad2, float* __restrict__ als,
                           float* __restrict__ ald) {
    int t = blockIdx.x * 256 + threadIdx.x;
    if (t >= NN) return;
    const unsigned int* xp = (const unsigned int*)(xs2b + (size_t)t * 32);
    float s = 0.f, d = 0.f;
    #pragma unroll
    for (int q = 0; q < 16; q++) {
        float2 v = bf2f2(xp[q]);
        s += v.x * as2[q * 2] + v.y * as2[q * 2 + 1];
        d += v.x * ad2[q * 2] + v.y * ad2[q * 2 + 1];
    }
    als[t] = s;
    ald[t] = d;
}

// ---------------- conv1 aggregation: one wave per dst node (H=4, F=128, bf16 gather) ----------------
__global__ __launch_bounds__(256) void gat1_agg(
    const unsigned short* __restrict__ xs1b, const float* __restrict__ als,
    const float* __restrict__ ald, const unsigned long long* __restrict__ edgedat,
    const int* __restrict__ indptr, const float* __restrict__ consts,
    const float* __restrict__ b1, const float* __restrict__ g1,
    const float* __restrict__ be1, float* __restrict__ h1out) {
    __shared__ float exbuf[4][CAP1 * 4];
    __shared__ int srcbuf[4][CAP1];
    int wv = threadIdx.x >> 6;
    int lane = threadIdx.x & 63;
    int n = blockIdx.x * 4 + wv;   // grid is exact: NN % 4 == 0
    int start = indptr[n];
    int deg = indptr[n + 1] - start;
    float ea_mean = consts[1];
    float ce[4] = {consts[2], consts[3], consts[4], consts[5]};
    float4 a4d = *(const float4*)(ald + (size_t)n * 4);
    float aldh[4] = {a4d.x, a4d.y, a4d.z, a4d.w};
    float4 a4s = *(const float4*)(als + (size_t)n * 4);
    float alsn[4] = {a4s.x, a4s.y, a4s.z, a4s.w};
    float asl[4], mx[4];
    #pragma unroll
    for (int h = 0; h < 4; h++) {
        float a = lrelu(alsn[h] + aldh[h] + ea_mean * ce[h]);
        asl[h] = a;
        mx[h] = a;
    }
    const unsigned long long* edp = edgedat + start;
    // phase 1: alpha + max
    for (int i = lane; i < deg; i += 64) {
        int s; float eav;
        unpack_edge(edp[i], s, eav);
        float4 v4 = *(const float4*)(als + (size_t)s * 4);
        float alv[4] = {v4.x, v4.y, v4.z, v4.w};
        bool st = (i < CAP1);
        if (st) srcbuf[wv][i] = s;
        #pragma unroll
        for (int h = 0; h < 4; h++) {
            float a = lrelu(alv[h] + aldh[h] + eav * ce[h]);
            if (st) exbuf[wv][i * 4 + h] = a;
            mx[h] = fmaxf(mx[h], a);
        }
    }
    #pragma unroll
    for (int h = 0; h < 4; h++)
        for (int off = 32; off > 0; off >>= 1) mx[h] = fmaxf(mx[h], __shfl_xor(mx[h], off));
    // phase 2: sum of exp (LDS-resident for deg<=CAP1, which is ~always)
    float sm[4] = {0.f, 0.f, 0.f, 0.f};
    for (int i = lane; i < deg; i += 64) {
        if (i < CAP1) {
            #pragma unroll
            for (int h = 0; h < 4; h++) {
                float exv = __expf(exbuf[wv][i * 4 + h] - mx[h]);
                exbuf[wv][i * 4 + h] = exv;
                sm[h] += exv;
            }
        } else {
            int s; float eav;
            unpack_edge(edp[i], s, eav);
            float4 v4 = *(const float4*)(als + (size_t)s * 4);
            float alv[4] = {v4.x, v4.y, v4.z, v4.w};
            #pragma unroll
            for (int h = 0; h < 4; h++) {
                float a = lrelu(alv[h] + aldh[h] + eav * ce[h]);
                sm[h] += __expf(a - mx[h]);
            }
        }
    }
    #pragma unroll
    for (int h = 0; h < 4; h++)
        for (int off = 32; off > 0; off >>= 1) sm[h] += __shfl_xor(sm[h], off);
    float inv[4];
    #pragma unroll
    for (int h = 0; h < 4; h++) inv[h] = 1.0f / (sm[h] + __expf(asl[h] - mx[h]) + 1e-16f);
    // phase 3: weighted gather (bf16); lane holds features c, c+1
    int c = lane * 2;
    int h = lane >> 4;
    float winv = inv[h];
    float wsl = __expf(asl[h] - mx[h]) * winv;
    float2 vself = bf2f2(*(const unsigned int*)(xs1b + (size_t)n * HC + c));
    float accx = vself.x * wsl, accy = vself.y * wsl;
    int m = deg < CAP1 ? deg : CAP1;
    int i = 0;
    for (; i + 4 <= m; i += 4) {
        float w0 = exbuf[wv][(i + 0) * 4 + h] * winv;
        float w1 = exbuf[wv][(i + 1) * 4 + h] * winv;
        float w2 = exbuf[wv][(i + 2) * 4 + h] * winv;
        float w3 = exbuf[wv][(i + 3) * 4 + h] * winv;
        int s0 = srcbuf[wv][i + 0], s1 = srcbuf[wv][i + 1];
        int s2 = srcbuf[wv][i + 2], s3 = srcbuf[wv][i + 3];
        float2 v0 = bf2f2(*(const unsigned int*)(xs1b + (size_t)s0 * HC + c));
        float2 v1 = bf2f2(*(const unsigned int*)(xs1b + (size_t)s1 * HC + c));
        float2 v2 = bf2f2(*(const unsigned int*)(xs1b + (size_t)s2 * HC + c));
        float2 v3 = bf2f2(*(const unsigned int*)(xs1b + (size_t)s3 * HC + c));
        accx += v0.x * w0; accy += v0.y * w0;
        accx += v1.x * w1; accy += v1.y * w1;
        accx += v2.x * w2; accy += v2.y * w2;
        accx += v3.x * w3; accy += v3.y * w3;
    }
    for (; i < m; i++) {
        float w0 = exbuf[wv][i * 4 + h] * winv;
        int s0 = srcbuf[wv][i];
        float2 v0 = bf2f2(*(const unsigned int*)(xs1b + (size_t)s0 * HC + c));
        accx += v0.x * w0; accy += v0.y * w0;
    }
    for (; i < deg; i++) {  // LDS-spill fallback (deg > CAP1): recompute
        int s; float eav;
        unpack_edge(edp[i], s, eav);
        float a = lrelu(als[(size_t)s * 4 + h] + aldh[h] + eav * ce[h]);
        float w0 = __expf(a - mx[h]) * winv;
        float2 v0 = bf2f2(*(const unsigned int*)(xs1b + (size_t)s * HC + c));
        accx += v0.x * w0; accy += v0.y * w0;
    }
    // epilogue: +bias, bn(eval), elu
    float o0 = accx + b1[c];
    float o1 = accy + b1[c + 1];
    o0 = o0 * (g1[c] * BN_RS) + be1[c];
    o1 = o1 * (g1[c + 1] * BN_RS) + be1[c + 1];
    o0 = elu(o0);
    o1 = elu(o1);
    *(float2*)(h1out + (size_t)n * HC + c) = make_float2(o0, o1);
}

// ---------------- conv2 aggregation + fused MLP heads ----------------
__global__ __launch_bounds__(256) void gat2_agg(
    const unsigned short* __restrict__ xs2b, const float* __restrict__ als,
    const float* __restrict__ ald, const unsigned long long* __restrict__ edgedat,
    const int* __restrict__ indptr, const float* __restrict__ consts,
    const float* __restrict__ b2, const float* __restrict__ g2, const float* __restrict__ be2,
    const float* __restrict__ Wc1, const float* __restrict__ bc1,
    const float* __restrict__ Wc2, const float* __restrict__ bc2,
    const float* __restrict__ Wr1, const float* __restrict__ br1,
    const float* __restrict__ Wr2, const float* __restrict__ br2,
    float* __restrict__ hout, float* __restrict__ cls, float* __restrict__ reg) {
    __shared__ float exbuf[4][CAP2];
    __shared__ int srcbuf[4][CAP2];
    __shared__ float hbuf[4][32];
    int wv = threadIdx.x >> 6;
    int lane = threadIdx.x & 63;
    int n = blockIdx.x * 4 + wv;   // grid exact
    int start = indptr[n];
    int deg = indptr[n + 1] - start;
    float ea_mean = consts[1];
    float ce = consts[6];
    float aldn = ald[n];
    float a0 = lrelu(als[n] + aldn + ea_mean * ce);
    float mx = a0;
    const unsigned long long* edp = edgedat + start;
    for (int i = lane; i < deg; i += 64) {
        int s; float eav;
        unpack_edge(edp[i], s, eav);
        float a = lrelu(als[s] + aldn + eav * ce);
        if (i < CAP2) { srcbuf[wv][i] = s; exbuf[wv][i] = a; }
        mx = fmaxf(mx, a);
    }
    for (int off = 32; off > 0; off >>= 1) mx = fmaxf(mx, __shfl_xor(mx, off));
    float sm = 0.f;
    for (int i = lane; i < deg; i += 64) {
        if (i < CAP2) {
            float exv = __expf(exbuf[wv][i] - mx);
            exbuf[wv][i] = exv;
            sm += exv;
        } else {
            int s; float eav;
            unpack_edge(edp[i], s, eav);
            float a = lrelu(als[s] + aldn + eav * ce);
            sm += __expf(a - mx);
        }
    }
    for (int off = 32; off > 0; off >>= 1) sm += __shfl_xor(sm, off);
    float invd = 1.0f / (sm + __expf(a0 - mx) + 1e-16f);
    // phase 3: 4 edges in parallel; 16 lanes/edge, 2 features per lane (bf16x2 = 4B)
    int quarter = lane >> 4;
    int cl = lane & 15;
    int c = cl * 2;
    float accx = 0.f, accy = 0.f;
    if (quarter == 0) {
        float2 vs = bf2f2(*(const unsigned int*)(xs2b + (size_t)n * CD + c));
        float wsl = __expf(a0 - mx) * invd;
        accx = vs.x * wsl; accy = vs.y * wsl;
    }
    int m = deg < CAP2 ? deg : CAP2;
    for (int i = quarter; i < m; i += 4) {
        float w0 = exbuf[wv][i] * invd;
        int s0 = srcbuf[wv][i];
        float2 v0 = bf2f2(*(const unsigned int*)(xs2b + (size_t)s0 * CD + c));
        accx += v0.x * w0; accy += v0.y * w0;
    }
    for (int i = CAP2 + quarter; i < deg; i += 4) {  // spill fallback
        int s; float eav;
        unpack_edge(edp[i], s, eav);
        float a = lrelu(als[s] + aldn + eav * ce);
        float w0 = __expf(a - mx) * invd;
        float2 v0 = bf2f2(*(const unsigned int*)(xs2b + (size_t)s * CD + c));
        accx += v0.x * w0; accy += v0.y * w0;
    }
    accx += __shfl_xor(accx, 16); accy += __shfl_xor(accy, 16);
    accx += __shfl_xor(accx, 32); accy += __shfl_xor(accy, 32);
    if (lane < 16) {
        float o0 = accx + b2[c];
        float o1 = accy + b2[c + 1];
        o0 = o0 * (g2[c] * BN_RS) + be2[c];
        o1 = o1 * (g2[c + 1] * BN_RS) + be2[c + 1];
        o0 = elu(o0);
        o1 = elu(o1);
        hbuf[wv][c] = o0;
        hbuf[wv][c + 1] = o1;
        *(float2*)(hout + (size_t)n * CD + c) = make_float2(o0, o1);
    }
    __syncthreads();
    // fused heads: lanes 0-15 classifier hidden unit j, lanes 16-31 regressor hidden unit j
    float r0 = 0.f, r1 = 0.f;
    if (lane < 32) {
        int j = lane & 15;
        bool iscls = lane < 16;
        float s = iscls ? bc1[j] : br1[j];
        #pragma unroll
        for (int cc = 0; cc < 32; cc++) {
            float w = iscls ? Wc1[cc * 16 + j] : Wr1[cc * 16 + j];
            s += hbuf[wv][cc] * w;
        }
        s = fmaxf(s, 0.f);
        if (iscls) { r0 = s * Wc2[j * 2]; r1 = s * Wc2[j * 2 + 1]; }
        else       { r0 = s * Wr2[j]; }
    }
    #pragma unroll
    for (int off = 1; off < 16; off <<= 1) {
        r0 += __shfl_xor(r0, off);
        r1 += __shfl_xor(r1, off);
    }
    if (lane == 0)  *(float2*)(cls + (size_t)n * 2) = make_float2(r0 + bc2[0], r1 + bc2[1]);
    if (lane == 16) reg[n] = r0 + br2[0];
}

// ---------------- launch ----------------
extern "C" void kernel_launch(void* const* d_in, const int* in_sizes, int n_in,
                              void* d_out, int out_size, void* d_ws, size_t ws_size,
                              hipStream_t stream) {
    const float* x   = (const float*)d_in[0];
    const int*   ei  = (const int*)d_in[1];
    const float* ea  = (const float*)d_in[2];
    const float* W1  = (const float*)d_in[3];
    const float* as1 = (const float*)d_in[4];
    const float* ad1 = (const float*)d_in[5];
    const float* We1 = (const float*)d_in[6];
    const float* ae1 = (const float*)d_in[7];
    const float* b1  = (const float*)d_in[8];
    const float* g1  = (const float*)d_in[9];
    const float* be1 = (const float*)d_in[10];
    const float* W2  = (const float*)d_in[11];
    const float* as2 = (const float*)d_in[12];
    const float* ad2 = (const float*)d_in[13];
    const float* We2 = (const float*)d_in[14];
    const float* ae2 = (const float*)d_in[15];
    const float* b2  = (const float*)d_in[16];
    const float* g2  = (const float*)d_in[17];
    const float* be2 = (const float*)d_in[18];
    const float* Wc1 = (const float*)d_in[19];
    const float* bc1 = (const float*)d_in[20];
    const float* Wc2 = (const float*)d_in[21];
    const float* bc2 = (const float*)d_in[22];
    const float* Wr1 = (const float*)d_in[23];
    const float* br1 = (const float*)d_in[24];
    const float* Wr2 = (const float*)d_in[25];
    const float* br2 = (const float*)d_in[26];

    char* ws = (char*)d_ws;
    unsigned short* xs1b = (unsigned short*)(ws + 0);          // N*128 bf16 = 12.8 MB
    float* h1            = (float*)(ws + 12800000);            // N*128 f32 = 25.6 MB
    unsigned short* xs2b = (unsigned short*)(ws + 38400000);   // N*32 bf16 = 3.2 MB
    float* als1          = (float*)(ws + 41600000);            // N*4
    float* ald1          = (float*)(ws + 42400000);            // N*4
    float* als2          = (float*)(ws + 43200000);            // N
    float* ald2          = (float*)(ws + 43400000);            // N
    float* consts        = (float*)(ws + 43600000);            // 8 floats
    int*   counts        = (int*)(ws + 43600128);              // N*CSTR ints = 6.4 MB (padded)
    int*   indptr        = (int*)(ws + 50000128);              // N+1 (padded to 16B)
    int*   partials      = (int*)(ws + 50200160);              // 64
    int*   localbuf      = (int*)(ws + 50200416);              // N
    int*   rank          = (int*)(ws + 50400416);              // E = 6.4 MB
    unsigned long long* edgedat = (unsigned long long*)(ws + 56800416);  // E*8 = 12.8 MB (ends ~69.6 MB)

    float* out_cls = (float*)d_out;            // [N,2]
    float* out_reg = out_cls + 2 * NN;         // [N]
    float* out_h   = out_cls + 3 * NN;         // [N,32]

    hipMemsetAsync(counts, 0, (size_t)NN * CSTR * sizeof(int), stream);
    hipMemsetAsync(consts, 0, 8 * sizeof(float), stream);

    // CSR build + edge mean (rank captured in count; scatter is atomic-free)
    count_kernel<<<(EE + 2047) / 2048, 256, 0, stream>>>(ei, ea, counts, rank, consts);
    scan_local<<<(NN + 1023) / 1024, 256, 0, stream>>>(counts, localbuf, partials, NN);
    scan_part<<<1, 64, 0, stream>>>(partials, indptr, (NN + 1023) / 1024);
    scan_add<<<(NN + 1023) / 1024, 256, 0, stream>>>(localbuf, partials, indptr, NN);
    scatter_kernel<<<(EE + 2047) / 2048, 256, 0, stream>>>(ei, ea, rank, indptr, edgedat);
    prep_kernel<<<1, 64, 0, stream>>>(We1, ae1, We2, ae2, consts);

    // conv1
    gemm_kernel<64, 128, 32, 4, 8, true><<<(NN + 63) / 64, 256, 0, stream>>>(x, W1, xs1b, NN, IN_DIM);
    al1_kernel<<<(NN * 4 + 255) / 256, 256, 0, stream>>>(xs1b, as1, ad1, als1, ald1);
    gat1_agg<<<NN / 4, 256, 0, stream>>>(xs1b, als1, ald1, edgedat, indptr, consts,
                                         b1, g1, be1, h1);
    // conv2
    gemm_kernel<128, 32, 32, 8, 2, true><<<(NN + 127) / 128, 256, 0, stream>>>(h1, W2, xs2b, NN, HC);
    al2_kernel<<<(NN + 255) / 256, 256, 0, stream>>>(xs2b, as2, ad2, als2, ald2);
    gat2_agg<<<NN / 4, 256, 0, stream>>>(xs2b, als2, ald2, edgedat, indptr, consts,
                                         b2, g2, be2, Wc1, bc1, Wc2, bc2,
                                         Wr1, br1, Wr2, br2, out_h, out_cls, out_reg);
}

// Round 6
// 459.664 us; speedup vs baseline: 1.1054x; 1.1054x over previous
//
#include <hip/hip_runtime.h>
#include <cstdint>
#include <cstddef>

// ---------------- problem constants ----------------
#define NN 50000
#define EE 1600000
#define IN_DIM 256
#define HC 128      // HEADS*C
#define CD 32       // C
#define BN_RS 0.9999950000374997f  // 1/sqrt(1+1e-5)

#define CAP1 128
#define CAP2 128
#define CNT_B 782   // == (EE+2047)/2048 == (NN+63)/64 == (NN*4+255)/256

// ---------------- small helpers ----------------
__device__ __forceinline__ float lrelu(float a) { return a > 0.f ? a : 0.2f * a; }
__device__ __forceinline__ float elu(float a) { return a > 0.f ? a : (__expf(a) - 1.f); }

__device__ __forceinline__ unsigned short f2bf(float f) {
    unsigned int u = __float_as_uint(f);
    unsigned int r = (u + 0x7FFFu + ((u >> 16) & 1u)) >> 16;
    return (unsigned short)r;
}
__device__ __forceinline__ float2 bf2f2(unsigned int p) {
    float2 r;
    r.x = __uint_as_float(p << 16);
    r.y = __uint_as_float(p & 0xFFFF0000u);
    return r;
}
__device__ __forceinline__ void unpack_edge(unsigned long long p, int& s, float& eav) {
    s = (int)(unsigned int)(p & 0xFFFFFFFFull);
    eav = __uint_as_float((unsigned int)(p >> 32));
}

// ---------------- K1: fused count (4-way split counters) + gemm1 ----------------
// Even blocks: count path (latency-bound atomics). Odd blocks: gemm1 (VALU-bound).
// The two paths share no data; fusing overlaps atomic latency with compute.
__global__ __launch_bounds__(256) void k1_count_gemm(
    const int* __restrict__ ei, const float* __restrict__ ea,
    const float* __restrict__ x, const float* __restrict__ W1,
    int* __restrict__ counts, int* __restrict__ rank, float* __restrict__ easum,
    unsigned short* __restrict__ xs1b) {
    __shared__ float As[32][64 + 4];
    __shared__ float Bs[32][128];
    int tid = threadIdx.x;
    int sub = blockIdx.x >> 1;
    if ((blockIdx.x & 1) == 0) {
        // ---- count path: 2048 edges per block, 8/thread ----
        int base = sub * 2048 + tid;
        float s = 0.f;
        #pragma unroll
        for (int k = 0; k < 8; k++) {
            int i = base + k * 256;
            if (i < EE) {
                int d = ei[EE + i];
                int r = atomicAdd(&counts[d * 4 + (i & 3)], 1);
                rank[i] = r;
                s += ea[i];
            }
        }
        #pragma unroll
        for (int off = 32; off > 0; off >>= 1) s += __shfl_xor(s, off);
        if ((tid & 63) == 0) atomicAdd(easum, s);
    } else {
        // ---- gemm1 path: TM=64,TN=128,TK=32,RM=4,RN=8, A=x[NN,256], B=W1[256,128] ----
        int tx = tid % 16;
        int ty = tid / 16;
        int blockRow = sub * 64;
        float acc[4][8];
        #pragma unroll
        for (int i = 0; i < 4; i++)
            #pragma unroll
            for (int j = 0; j < 8; j++) acc[i][j] = 0.f;
        for (int k0 = 0; k0 < IN_DIM; k0 += 32) {
            #pragma unroll
            for (int l = 0; l < 2048; l += 1024) {
                int ll = l + tid * 4;
                int r = ll / 32, kk = ll % 32;
                float4 v = make_float4(0.f, 0.f, 0.f, 0.f);
                int gr = blockRow + r;
                if (gr < NN) v = *(const float4*)(x + (size_t)gr * IN_DIM + k0 + kk);
                As[kk + 0][r] = v.x;
                As[kk + 1][r] = v.y;
                As[kk + 2][r] = v.z;
                As[kk + 3][r] = v.w;
            }
            #pragma unroll
            for (int l = 0; l < 4096; l += 1024) {
                int ll = l + tid * 4;
                int kk = ll / 128, c = ll % 128;
                *(float4*)&Bs[kk][c] = *(const float4*)(W1 + (size_t)(k0 + kk) * 128 + c);
            }
            __syncthreads();
            #pragma unroll
            for (int k = 0; k < 32; k++) {
                float af[4], bf[8];
                #pragma unroll
                for (int i = 0; i < 4; i++) af[i] = As[k][ty * 4 + i];
                #pragma unroll
                for (int j = 0; j < 8; j++) bf[j] = Bs[k][tx * 8 + j];
                #pragma unroll
                for (int i = 0; i < 4; i++)
                    #pragma unroll
                    for (int j = 0; j < 8; j++) acc[i][j] += af[i] * bf[j];
            }
            __syncthreads();
        }
        #pragma unroll
        for (int i = 0; i < 4; i++) {
            int gr = blockRow + ty * 4 + i;
            if (gr < NN) {
                #pragma unroll
                for (int j = 0; j < 8; j += 2) {
                    unsigned int pk = (unsigned int)f2bf(acc[i][j]) |
                                      ((unsigned int)f2bf(acc[i][j + 1]) << 16);
                    *(unsigned int*)(xs1b + (size_t)gr * HC + tx * 8 + j) = pk;
                }
            }
        }
    }
}

// ---------------- hierarchical scan ----------------
__global__ __launch_bounds__(256) void scan_local(const int* __restrict__ counts,
                                                  int* __restrict__ localbuf,
                                                  int* __restrict__ partials, int n) {
    __shared__ int wsum[4];
    int tid = threadIdx.x, lane = tid & 63, wv = tid >> 6;
    int i = blockIdx.x * 1024 + tid * 4;
    int v0 = 0, v1 = 0, v2 = 0, v3 = 0;
    if (i < n) {
        int4 c0 = *(const int4*)(counts + (size_t)(i + 0) * 4);
        int4 c1 = *(const int4*)(counts + (size_t)(i + 1) * 4);
        int4 c2 = *(const int4*)(counts + (size_t)(i + 2) * 4);
        int4 c3 = *(const int4*)(counts + (size_t)(i + 3) * 4);
        v0 = c0.x + c0.y + c0.z + c0.w;
        v1 = c1.x + c1.y + c1.z + c1.w;
        v2 = c2.x + c2.y + c2.z + c2.w;
        v3 = c3.x + c3.y + c3.z + c3.w;
    }
    int t = v0 + v1 + v2 + v3;
    int x = t;
    #pragma unroll
    for (int off = 1; off < 64; off <<= 1) {
        int y = __shfl_up(x, off);
        if (lane >= off) x += y;
    }
    if (lane == 63) wsum[wv] = x;
    __syncthreads();
    int wpre = 0;
    #pragma unroll
    for (int w = 0; w < 4; w++)
        if (w < wv) wpre += wsum[w];
    if (i < n) {
        int e0 = wpre + x - t;
        int4 o;
        o.x = e0; o.y = e0 + v0; o.z = o.y + v1; o.w = o.z + v2;
        *(int4*)(localbuf + i) = o;
    }
    if (tid == 0) partials[blockIdx.x] = wsum[0] + wsum[1] + wsum[2] + wsum[3];
}

__global__ void scan_part(int* __restrict__ partials, int* __restrict__ indptr, int nblk) {
    int lane = threadIdx.x;  // 64 threads
    int v = (lane < nblk) ? partials[lane] : 0;
    int x = v;
    #pragma unroll
    for (int off = 1; off < 64; off <<= 1) {
        int y = __shfl_up(x, off);
        if (lane >= off) x += y;
    }
    if (lane < nblk) partials[lane] = x - v;
    if (lane == 0) indptr[NN] = EE;
}

// writes indptr (node-level) and base4 (node x 4 sub-class exclusive bases)
__global__ __launch_bounds__(256) void scan_add(const int* __restrict__ localbuf,
                                                const int* __restrict__ partials,
                                                const int* __restrict__ counts,
                                                int* __restrict__ indptr,
                                                int* __restrict__ base4, int n) {
    int i = blockIdx.x * 1024 + threadIdx.x * 4;
    if (i < n) {
        int off = partials[blockIdx.x];
        int4 t = *(const int4*)(localbuf + i);
        t.x += off; t.y += off; t.z += off; t.w += off;
        *(int4*)(indptr + i) = t;
        int E0s[4] = {t.x, t.y, t.z, t.w};
        #pragma unroll
        for (int j = 0; j < 4; j++) {
            int4 c = *(const int4*)(counts + (size_t)(i + j) * 4);
            int4 b;
            b.x = E0s[j];
            b.y = b.x + c.x;
            b.z = b.y + c.y;
            b.w = b.z + c.z;
            *(int4*)(base4 + (size_t)(i + j) * 4) = b;
        }
    }
}

// ---------------- K2: fused scatter (atomic-free) + al1 ----------------
__global__ __launch_bounds__(256) void k2_scatter_al1(
    const int* __restrict__ ei, const float* __restrict__ ea,
    const int* __restrict__ rank, const int* __restrict__ base4,
    unsigned long long* __restrict__ edgedat,
    const unsigned short* __restrict__ xs1b, const float* __restrict__ as1,
    const float* __restrict__ ad1, float* __restrict__ als, float* __restrict__ ald) {
    int tid = threadIdx.x;
    int sub = blockIdx.x >> 1;
    if ((blockIdx.x & 1) == 0) {
        // ---- scatter path ----
        int base = sub * 2048 + tid;
        #pragma unroll
        for (int k = 0; k < 8; k++) {
            int i = base + k * 256;
            if (i < EE) {
                int src = ei[i];
                int d = ei[EE + i];
                float eav = ea[i];
                int pos = base4[d * 4 + (i & 3)] + rank[i];
                edgedat[pos] = (unsigned long long)(unsigned int)src |
                               ((unsigned long long)__float_as_uint(eav) << 32);
            }
        }
    } else {
        // ---- al1 path: one thread per (node,head) ----
        int t = sub * 256 + tid;
        if (t < NN * 4) {
            int h = t & 3;
            const unsigned int* xp = (const unsigned int*)(xs1b + (size_t)t * 32);
            const float* ap = as1 + h * 32;
            const float* dp = ad1 + h * 32;
            float s = 0.f, d = 0.f;
            #pragma unroll
            for (int q = 0; q < 16; q++) {
                float2 v = bf2f2(xp[q]);
                s += v.x * ap[q * 2] + v.y * ap[q * 2 + 1];
                d += v.x * dp[q * 2] + v.y * dp[q * 2 + 1];
            }
            als[t] = s;
            ald[t] = d;
        }
    }
}

// ---------------- per-head attention constants + ea mean ----------------
__global__ void prep_kernel(const float* __restrict__ We1, const float* __restrict__ ae1,
                            const float* __restrict__ We2, const float* __restrict__ ae2,
                            float* __restrict__ consts) {
    int lane = threadIdx.x;
    if (lane < 4) {
        float s = 0.f;
        for (int c = 0; c < 32; c++) s += We1[lane * 32 + c] * ae1[lane * 32 + c];
        consts[2 + lane] = s;
    } else if (lane == 4) {
        float s = 0.f;
        for (int c = 0; c < 32; c++) s += We2[c] * ae2[c];
        consts[6] = s;
    } else if (lane == 5) {
        consts[1] = consts[0] / (float)EE;
    }
}

// ---------------- fp32 tiled GEMM (used for gemm2) ----------------
template <int TM, int TN, int TK, int RM, int RN, bool BF16OUT>
__global__ __launch_bounds__(256) void gemm_kernel(const float* __restrict__ A,
                                                   const float* __restrict__ B,
                                                   void* __restrict__ Cv, int M, int K) {
    static_assert(TM * TN == 256 * RM * RN, "thread coverage");
    static_assert(RN % 2 == 0, "pairable");
    __shared__ float As[TK][TM + 4];
    __shared__ float Bs[TK][TN];
    int tid = threadIdx.x;
    int tx = tid % (TN / RN);
    int ty = tid / (TN / RN);
    int blockRow = blockIdx.x * TM;
    float acc[RM][RN];
    #pragma unroll
    for (int i = 0; i < RM; i++)
        #pragma unroll
        for (int j = 0; j < RN; j++) acc[i][j] = 0.f;

    for (int k0 = 0; k0 < K; k0 += TK) {
        #pragma unroll
        for (int l = 0; l < TM * TK; l += 256 * 4) {
            int ll = l + tid * 4;
            if (ll < TM * TK) {
                int r = ll / TK, kk = ll % TK;
                float4 v = make_float4(0.f, 0.f, 0.f, 0.f);
                int gr = blockRow + r;
                if (gr < M) v = *(const float4*)(A + (size_t)gr * K + k0 + kk);
                As[kk + 0][r] = v.x;
                As[kk + 1][r] = v.y;
                As[kk + 2][r] = v.z;
                As[kk + 3][r] = v.w;
            }
        }
        #pragma unroll
        for (int l = 0; l < TK * TN; l += 256 * 4) {
            int ll = l + tid * 4;
            if (ll < TK * TN) {
                int kk = ll / TN, c = ll % TN;
                *(float4*)&Bs[kk][c] = *(const float4*)(B + (size_t)(k0 + kk) * TN + c);
            }
        }
        __syncthreads();
        #pragma unroll
        for (int k = 0; k < TK; k++) {
            float af[RM], bf[RN];
            #pragma unroll
            for (int i = 0; i < RM; i++) af[i] = As[k][ty * RM + i];
            #pragma unroll
            for (int j = 0; j < RN; j++) bf[j] = Bs[k][tx * RN + j];
            #pragma unroll
            for (int i = 0; i < RM; i++)
                #pragma unroll
                for (int j = 0; j < RN; j++) acc[i][j] += af[i] * bf[j];
        }
        __syncthreads();
    }
    #pragma unroll
    for (int i = 0; i < RM; i++) {
        int gr = blockRow + ty * RM + i;
        if (gr < M) {
            if (BF16OUT) {
                unsigned short* C = (unsigned short*)Cv;
                #pragma unroll
                for (int j = 0; j < RN; j += 2) {
                    unsigned int pk = (unsigned int)f2bf(acc[i][j]) |
                                      ((unsigned int)f2bf(acc[i][j + 1]) << 16);
                    *(unsigned int*)(C + (size_t)gr * TN + tx * RN + j) = pk;
                }
            } else {
                float* C = (float*)Cv;
                #pragma unroll
                for (int j = 0; j < RN; j++) C[(size_t)gr * TN + tx * RN + j] = acc[i][j];
            }
        }
    }
}

// ---------------- attention logits for conv2 ----------------
__global__ void al2_kernel(const unsigned short* __restrict__ xs2b, const float* __restrict__ as2,
                           const float* __restrict__ ad2, float* __restrict__ als,
                           float* __restrict__ ald) {
    int t = blockIdx.x * 256 + threadIdx.x;
    if (t >= NN) return;
    const unsigned int* xp = (const unsigned int*)(xs2b + (size_t)t * 32);
    float s = 0.f, d = 0.f;
    #pragma unroll
    for (int q = 0; q < 16; q++) {
        float2 v = bf2f2(xp[q]);
        s += v.x * as2[q * 2] + v.y * as2[q * 2 + 1];
        d += v.x * ad2[q * 2] + v.y * ad2[q * 2 + 1];
    }
    als[t] = s;
    ald[t] = d;
}

// ---------------- conv1 aggregation: one wave per dst node (H=4, F=128, bf16 gather) ----------------
__global__ __launch_bounds__(256) void gat1_agg(
    const unsigned short* __restrict__ xs1b, const float* __restrict__ als,
    const float* __restrict__ ald, const unsigned long long* __restrict__ edgedat,
    const int* __restrict__ indptr, const float* __restrict__ consts,
    const float* __restrict__ b1, const float* __restrict__ g1,
    const float* __restrict__ be1, float* __restrict__ h1out) {
    __shared__ float exbuf[4][CAP1 * 4];
    __shared__ int srcbuf[4][CAP1];
    int wv = threadIdx.x >> 6;
    int lane = threadIdx.x & 63;
    int n = blockIdx.x * 4 + wv;   // grid exact: NN % 4 == 0
    int start = indptr[n];
    int deg = indptr[n + 1] - start;
    float ea_mean = consts[1];
    float ce[4] = {consts[2], consts[3], consts[4], consts[5]};
    float4 a4d = *(const float4*)(ald + (size_t)n * 4);
    float aldh[4] = {a4d.x, a4d.y, a4d.z, a4d.w};
    float4 a4s = *(const float4*)(als + (size_t)n * 4);
    float alsn[4] = {a4s.x, a4s.y, a4s.z, a4s.w};
    float asl[4], mx[4];
    #pragma unroll
    for (int h = 0; h < 4; h++) {
        float a = lrelu(alsn[h] + aldh[h] + ea_mean * ce[h]);
        asl[h] = a;
        mx[h] = a;
    }
    const unsigned long long* edp = edgedat + start;
    // phase 1: alpha + max
    for (int i = lane; i < deg; i += 64) {
        int s; float eav;
        unpack_edge(edp[i], s, eav);
        float4 v4 = *(const float4*)(als + (size_t)s * 4);
        float alv[4] = {v4.x, v4.y, v4.z, v4.w};
        bool st = (i < CAP1);
        if (st) srcbuf[wv][i] = s;
        #pragma unroll
        for (int h = 0; h < 4; h++) {
            float a = lrelu(alv[h] + aldh[h] + eav * ce[h]);
            if (st) exbuf[wv][i * 4 + h] = a;
            mx[h] = fmaxf(mx[h], a);
        }
    }
    #pragma unroll
    for (int h = 0; h < 4; h++)
        for (int off = 32; off > 0; off >>= 1) mx[h] = fmaxf(mx[h], __shfl_xor(mx[h], off));
    // phase 2: sum of exp
    float sm[4] = {0.f, 0.f, 0.f, 0.f};
    for (int i = lane; i < deg; i += 64) {
        if (i < CAP1) {
            #pragma unroll
            for (int h = 0; h < 4; h++) {
                float exv = __expf(exbuf[wv][i * 4 + h] - mx[h]);
                exbuf[wv][i * 4 + h] = exv;
                sm[h] += exv;
            }
        } else {
            int s; float eav;
            unpack_edge(edp[i], s, eav);
            float4 v4 = *(const float4*)(als + (size_t)s * 4);
            float alv[4] = {v4.x, v4.y, v4.z, v4.w};
            #pragma unroll
            for (int h = 0; h < 4; h++) {
                float a = lrelu(alv[h] + aldh[h] + eav * ce[h]);
                sm[h] += __expf(a - mx[h]);
            }
        }
    }
    #pragma unroll
    for (int h = 0; h < 4; h++)
        for (int off = 32; off > 0; off >>= 1) sm[h] += __shfl_xor(sm[h], off);
    float inv[4];
    #pragma unroll
    for (int h = 0; h < 4; h++) inv[h] = 1.0f / (sm[h] + __expf(asl[h] - mx[h]) + 1e-16f);
    // phase 3: weighted gather (bf16); lane holds features c, c+1
    int c = lane * 2;
    int h = lane >> 4;
    float winv = inv[h];
    float wsl = __expf(asl[h] - mx[h]) * winv;
    float2 vself = bf2f2(*(const unsigned int*)(xs1b + (size_t)n * HC + c));
    float accx = vself.x * wsl, accy = vself.y * wsl;
    int m = deg < CAP1 ? deg : CAP1;
    int i = 0;
    for (; i + 4 <= m; i += 4) {
        float w0 = exbuf[wv][(i + 0) * 4 + h] * winv;
        float w1 = exbuf[wv][(i + 1) * 4 + h] * winv;
        float w2 = exbuf[wv][(i + 2) * 4 + h] * winv;
        float w3 = exbuf[wv][(i + 3) * 4 + h] * winv;
        int s0 = srcbuf[wv][i + 0], s1 = srcbuf[wv][i + 1];
        int s2 = srcbuf[wv][i + 2], s3 = srcbuf[wv][i + 3];
        float2 v0 = bf2f2(*(const unsigned int*)(xs1b + (size_t)s0 * HC + c));
        float2 v1 = bf2f2(*(const unsigned int*)(xs1b + (size_t)s1 * HC + c));
        float2 v2 = bf2f2(*(const unsigned int*)(xs1b + (size_t)s2 * HC + c));
        float2 v3 = bf2f2(*(const unsigned int*)(xs1b + (size_t)s3 * HC + c));
        accx += v0.x * w0; accy += v0.y * w0;
        accx += v1.x * w1; accy += v1.y * w1;
        accx += v2.x * w2; accy += v2.y * w2;
        accx += v3.x * w3; accy += v3.y * w3;
    }
    for (; i < m; i++) {
        float w0 = exbuf[wv][i * 4 + h] * winv;
        int s0 = srcbuf[wv][i];
        float2 v0 = bf2f2(*(const unsigned int*)(xs1b + (size_t)s0 * HC + c));
        accx += v0.x * w0; accy += v0.y * w0;
    }
    for (; i < deg; i++) {  // spill fallback
        int s; float eav;
        unpack_edge(edp[i], s, eav);
        float a = lrelu(als[(size_t)s * 4 + h] + aldh[h] + eav * ce[h]);
        float w0 = __expf(a - mx[h]) * winv;
        float2 v0 = bf2f2(*(const unsigned int*)(xs1b + (size_t)s * HC + c));
        accx += v0.x * w0; accy += v0.y * w0;
    }
    float o0 = accx + b1[c];
    float o1 = accy + b1[c + 1];
    o0 = o0 * (g1[c] * BN_RS) + be1[c];
    o1 = o1 * (g1[c + 1] * BN_RS) + be1[c + 1];
    o0 = elu(o0);
    o1 = elu(o1);
    *(float2*)(h1out + (size_t)n * HC + c) = make_float2(o0, o1);
}

// ---------------- conv2 aggregation + fused MLP heads ----------------
__global__ __launch_bounds__(256) void gat2_agg(
    const unsigned short* __restrict__ xs2b, const float* __restrict__ als,
    const float* __restrict__ ald, const unsigned long long* __restrict__ edgedat,
    const int* __restrict__ indptr, const float* __restrict__ consts,
    const float* __restrict__ b2, const float* __restrict__ g2, const float* __restrict__ be2,
    const float* __restrict__ Wc1, const float* __restrict__ bc1,
    const float* __restrict__ Wc2, const float* __restrict__ bc2,
    const float* __restrict__ Wr1, const float* __restrict__ br1,
    const float* __restrict__ Wr2, const float* __restrict__ br2,
    float* __restrict__ hout, float* __restrict__ cls, float* __restrict__ reg) {
    __shared__ float exbuf[4][CAP2];
    __shared__ int srcbuf[4][CAP2];
    __shared__ float hbuf[4][32];
    int wv = threadIdx.x >> 6;
    int lane = threadIdx.x & 63;
    int n = blockIdx.x * 4 + wv;   // grid exact
    int start = indptr[n];
    int deg = indptr[n + 1] - start;
    float ea_mean = consts[1];
    float ce = consts[6];
    float aldn = ald[n];
    float a0 = lrelu(als[n] + aldn + ea_mean * ce);
    float mx = a0;
    const unsigned long long* edp = edgedat + start;
    for (int i = lane; i < deg; i += 64) {
        int s; float eav;
        unpack_edge(edp[i], s, eav);
        float a = lrelu(als[s] + aldn + eav * ce);
        if (i < CAP2) { srcbuf[wv][i] = s; exbuf[wv][i] = a; }
        mx = fmaxf(mx, a);
    }
    for (int off = 32; off > 0; off >>= 1) mx = fmaxf(mx, __shfl_xor(mx, off));
    float sm = 0.f;
    for (int i = lane; i < deg; i += 64) {
        if (i < CAP2) {
            float exv = __expf(exbuf[wv][i] - mx);
            exbuf[wv][i] = exv;
            sm += exv;
        } else {
            int s; float eav;
            unpack_edge(edp[i], s, eav);
            float a = lrelu(als[s] + aldn + eav * ce);
            sm += __expf(a - mx);
        }
    }
    for (int off = 32; off > 0; off >>= 1) sm += __shfl_xor(sm, off);
    float invd = 1.0f / (sm + __expf(a0 - mx) + 1e-16f);
    int quarter = lane >> 4;
    int cl = lane & 15;
    int c = cl * 2;
    float accx = 0.f, accy = 0.f;
    if (quarter == 0) {
        float2 vs = bf2f2(*(const unsigned int*)(xs2b + (size_t)n * CD + c));
        float wsl = __expf(a0 - mx) * invd;
        accx = vs.x * wsl; accy = vs.y * wsl;
    }
    int m = deg < CAP2 ? deg : CAP2;
    for (int i = quarter; i < m; i += 4) {
        float w0 = exbuf[wv][i] * invd;
        int s0 = srcbuf[wv][i];
        float2 v0 = bf2f2(*(const unsigned int*)(xs2b + (size_t)s0 * CD + c));
        accx += v0.x * w0; accy += v0.y * w0;
    }
    for (int i = CAP2 + quarter; i < deg; i += 4) {  // spill fallback
        int s; float eav;
        unpack_edge(edp[i], s, eav);
        float a = lrelu(als[s] + aldn + eav * ce);
        float w0 = __expf(a - mx) * invd;
        float2 v0 = bf2f2(*(const unsigned int*)(xs2b + (size_t)s * CD + c));
        accx += v0.x * w0; accy += v0.y * w0;
    }
    accx += __shfl_xor(accx, 16); accy += __shfl_xor(accy, 16);
    accx += __shfl_xor(accx, 32); accy += __shfl_xor(accy, 32);
    if (lane < 16) {
        float o0 = accx + b2[c];
        float o1 = accy + b2[c + 1];
        o0 = o0 * (g2[c] * BN_RS) + be2[c];
        o1 = o1 * (g2[c + 1] * BN_RS) + be2[c + 1];
        o0 = elu(o0);
        o1 = elu(o1);
        hbuf[wv][c] = o0;
        hbuf[wv][c + 1] = o1;
        *(float2*)(hout + (size_t)n * CD + c) = make_float2(o0, o1);
    }
    __syncthreads();
    float r0 = 0.f, r1 = 0.f;
    if (lane < 32) {
        int j = lane & 15;
        bool iscls = lane < 16;
        float s = iscls ? bc1[j] : br1[j];
        #pragma unroll
        for (int cc = 0; cc < 32; cc++) {
            float w = iscls ? Wc1[cc * 16 + j] : Wr1[cc * 16 + j];
            s += hbuf[wv][cc] * w;
        }
        s = fmaxf(s, 0.f);
        if (iscls) { r0 = s * Wc2[j * 2]; r1 = s * Wc2[j * 2 + 1]; }
        else       { r0 = s * Wr2[j]; }
    }
    #pragma unroll
    for (int off = 1; off < 16; off <<= 1) {
        r0 += __shfl_xor(r0, off);
        r1 += __shfl_xor(r1, off);
    }
    if (lane == 0)  *(float2*)(cls + (size_t)n * 2) = make_float2(r0 + bc2[0], r1 + bc2[1]);
    if (lane == 16) reg[n] = r0 + br2[0];
}

// ---------------- launch ----------------
extern "C" void kernel_launch(void* const* d_in, const int* in_sizes, int n_in,
                              void* d_out, int out_size, void* d_ws, size_t ws_size,
                              hipStream_t stream) {
    const float* x   = (const float*)d_in[0];
    const int*   ei  = (const int*)d_in[1];
    const float* ea  = (const float*)d_in[2];
    const float* W1  = (const float*)d_in[3];
    const float* as1 = (const float*)d_in[4];
    const float* ad1 = (const float*)d_in[5];
    const float* We1 = (const float*)d_in[6];
    const float* ae1 = (const float*)d_in[7];
    const float* b1  = (const float*)d_in[8];
    const float* g1  = (const float*)d_in[9];
    const float* be1 = (const float*)d_in[10];
    const float* W2  = (const float*)d_in[11];
    const float* as2 = (const float*)d_in[12];
    const float* ad2 = (const float*)d_in[13];
    const float* We2 = (const float*)d_in[14];
    const float* ae2 = (const float*)d_in[15];
    const float* b2  = (const float*)d_in[16];
    const float* g2  = (const float*)d_in[17];
    const float* be2 = (const float*)d_in[18];
    const float* Wc1 = (const float*)d_in[19];
    const float* bc1 = (const float*)d_in[20];
    const float* Wc2 = (const float*)d_in[21];
    const float* bc2 = (const float*)d_in[22];
    const float* Wr1 = (const float*)d_in[23];
    const float* br1 = (const float*)d_in[24];
    const float* Wr2 = (const float*)d_in[25];
    const float* br2 = (const float*)d_in[26];

    char* ws = (char*)d_ws;
    unsigned short* xs1b = (unsigned short*)(ws + 0);          // N*128 bf16 = 12.8 MB
    float* h1            = (float*)(ws + 12800000);            // N*128 f32 = 25.6 MB
    unsigned short* xs2b = (unsigned short*)(ws + 38400000);   // N*32 bf16 = 3.2 MB
    float* als1          = (float*)(ws + 41600000);            // N*4
    float* ald1          = (float*)(ws + 42400000);            // N*4
    float* als2          = (float*)(ws + 43200000);            // N
    float* ald2          = (float*)(ws + 43400000);            // N
    float* consts        = (float*)(ws + 43600000);            // 8 floats
    int*   counts        = (int*)(ws + 43600128);              // N*4 ints = 800 KB
    int*   base4         = (int*)(ws + 44400128);              // N*4 ints = 800 KB
    int*   indptr        = (int*)(ws + 45200128);              // N+1
    int*   partials      = (int*)(ws + 45400160);              // 64
    int*   localbuf      = (int*)(ws + 45400416);              // N
    int*   rank          = (int*)(ws + 45600416);              // E = 6.4 MB
    unsigned long long* edgedat = (unsigned long long*)(ws + 52000416);  // E*8 = 12.8 MB

    float* out_cls = (float*)d_out;            // [N,2]
    float* out_reg = out_cls + 2 * NN;         // [N]
    float* out_h   = out_cls + 3 * NN;         // [N,32]

    hipMemsetAsync(counts, 0, (size_t)NN * 4 * sizeof(int), stream);
    hipMemsetAsync(consts, 0, 8 * sizeof(float), stream);

    // K1: count (split counters) + gemm1, interleaved blocks
    k1_count_gemm<<<2 * CNT_B, 256, 0, stream>>>(ei, ea, x, W1, counts, rank, consts, xs1b);
    scan_local<<<(NN + 1023) / 1024, 256, 0, stream>>>(counts, localbuf, partials, NN);
    scan_part<<<1, 64, 0, stream>>>(partials, indptr, (NN + 1023) / 1024);
    scan_add<<<(NN + 1023) / 1024, 256, 0, stream>>>(localbuf, partials, counts, indptr, base4, NN);
    // K2: scatter (atomic-free) + al1
    k2_scatter_al1<<<2 * CNT_B, 256, 0, stream>>>(ei, ea, rank, base4, edgedat,
                                                  xs1b, as1, ad1, als1, ald1);
    prep_kernel<<<1, 64, 0, stream>>>(We1, ae1, We2, ae2, consts);

    gat1_agg<<<NN / 4, 256, 0, stream>>>(xs1b, als1, ald1, edgedat, indptr, consts,
                                         b1, g1, be1, h1);
    // conv2
    gemm_kernel<128, 32, 32, 8, 2, true><<<(NN + 127) / 128, 256, 0, stream>>>(h1, W2, xs2b, NN, HC);
    al2_kernel<<<(NN + 255) / 256, 256, 0, stream>>>(xs2b, as2, ad2, als2, ald2);
    gat2_agg<<<NN / 4, 256, 0, stream>>>(xs2b, als2, ald2, edgedat, indptr, consts,
                                         b2, g2, be2, Wc1, bc1, Wc2, bc2,
                                         Wr1, br1, Wr2, br2, out_h, out_cls, out_reg);
}

// Round 7
// 446.489 us; speedup vs baseline: 1.1380x; 1.0295x over previous
//
#include <hip/hip_runtime.h>
#include <cstdint>
#include <cstddef>

// ---------------- problem constants ----------------
#define NN 50000
#define EE 1600000
#define IN_DIM 256
#define HC 128      // HEADS*C
#define CD 32       // C
#define BN_RS 0.9999950000374997f  // 1/sqrt(1+1e-5)

#define CAP1 128
#define CAP2 128
#define NBKT 196        // ceil(NN/256) buckets of 256 dst nodes
#define S1_B 782        // (EE+2047)/2048

// ---------------- small helpers ----------------
__device__ __forceinline__ float lrelu(float a) { return a > 0.f ? a : 0.2f * a; }
__device__ __forceinline__ float elu(float a) { return a > 0.f ? a : (__expf(a) - 1.f); }

__device__ __forceinline__ unsigned short f2bf(float f) {
    unsigned int u = __float_as_uint(f);
    unsigned int r = (u + 0x7FFFu + ((u >> 16) & 1u)) >> 16;
    return (unsigned short)r;
}
__device__ __forceinline__ float2 bf2f2(unsigned int p) {
    float2 r;
    r.x = __uint_as_float(p << 16);
    r.y = __uint_as_float(p & 0xFFFF0000u);
    return r;
}
__device__ __forceinline__ void unpack_edge(unsigned long long p, int& s, float& eav) {
    s = (int)(unsigned int)(p & 0xFFFFFFFFull);
    eav = __uint_as_float((unsigned int)(p >> 32));
}

// 256-thread exclusive scan (contains ONE internal barrier; all 256 must call)
__device__ __forceinline__ int block_excl_scan_256(int v, int tid, int* wsum) {
    int lane = tid & 63, wv = tid >> 6;
    int x = v;
    #pragma unroll
    for (int off = 1; off < 64; off <<= 1) {
        int y = __shfl_up(x, off);
        if (lane >= off) x += y;
    }
    if (lane == 63) wsum[wv] = x;
    __syncthreads();
    int wpre = 0;
    #pragma unroll
    for (int w = 0; w < 4; w++)
        if (w < wv) wpre += wsum[w];
    return wpre + x - v;
}

// ---------------- hist: 196-bin bucket histogram (LDS) + ea sum ----------------
__global__ __launch_bounds__(256) void hist_kernel(const int* __restrict__ ei,
                                                   const float* __restrict__ ea,
                                                   int* __restrict__ bucketHist,
                                                   float* __restrict__ easum) {
    __shared__ int h[256];
    int tid = threadIdx.x;
    h[tid] = 0;
    __syncthreads();
    float s = 0.f;
    for (int i = blockIdx.x * 256 + tid; i < EE; i += gridDim.x * 256) {
        atomicAdd(&h[ei[EE + i] >> 8], 1);
        s += ea[i];
    }
    __syncthreads();
    if (tid < NBKT && h[tid] > 0) atomicAdd(&bucketHist[tid], h[tid]);
    #pragma unroll
    for (int off = 32; off > 0; off >>= 1) s += __shfl_xor(s, off);
    if ((tid & 63) == 0) atomicAdd(easum, s);
}

// ---------------- bucket scan: bases + cursors + tail sentinels ----------------
__global__ void bucket_scan(const int* __restrict__ bucketHist,
                            int* __restrict__ bucketBase,
                            int* __restrict__ bucketCursor,
                            int* __restrict__ indptr) {
    __shared__ int wsum[4];
    int tid = threadIdx.x;  // 256
    int v = (tid < NBKT) ? bucketHist[tid] : 0;
    int excl = block_excl_scan_256(v, tid, wsum);
    if (tid <= NBKT) bucketBase[tid] = (tid == NBKT) ? EE : excl;
    if (tid < NBKT) bucketCursor[tid] = excl;
    if (tid == 0) indptr[NN] = EE;
}

// ---------------- stage1: LDS bin by bucket, block-reserve, segment-coalesced copy-out ----
__global__ __launch_bounds__(256) void stage1_kernel(const int* __restrict__ ei,
                                                     const float* __restrict__ ea,
                                                     int* __restrict__ bucketCursor,
                                                     int* __restrict__ Adst,
                                                     int* __restrict__ Asrc,
                                                     float* __restrict__ Aea) {
    __shared__ int cnt[256];
    __shared__ int basel[256];
    __shared__ int gbase[256];
    __shared__ int wsum[4];
    __shared__ int sdst[2048];
    __shared__ int ssrc[2048];
    __shared__ float sea[2048];
    int tid = threadIdx.x;
    int base = blockIdx.x * 2048;
    cnt[tid] = 0;
    __syncthreads();
    int d[8], s[8], r[8], bk[8];
    float e[8];
    #pragma unroll
    for (int k = 0; k < 8; k++) {
        int i = base + k * 256 + tid;
        if (i < EE) {
            d[k] = ei[EE + i];
            s[k] = ei[i];
            e[k] = ea[i];
            bk[k] = d[k] >> 8;
            r[k] = atomicAdd(&cnt[bk[k]], 1);   // LDS returning atomic: cheap
        } else d[k] = -1;
    }
    __syncthreads();
    int v = cnt[tid];
    int excl = block_excl_scan_256(v, tid, wsum);
    basel[tid] = excl;
    if (tid < NBKT) gbase[tid] = atomicAdd(&bucketCursor[tid], v);  // 196 global atomics/block
    __syncthreads();
    #pragma unroll
    for (int k = 0; k < 8; k++) {
        if (d[k] >= 0) {
            int slot = basel[bk[k]] + r[k];
            sdst[slot] = d[k];
            ssrc[slot] = s[k];
            sea[slot] = e[k];
        }
    }
    __syncthreads();
    int total = basel[255] + cnt[255];
    for (int slot = tid; slot < total; slot += 256) {
        int dd = sdst[slot];
        int b = dd >> 8;
        int pos = gbase[b] + (slot - basel[b]);
        Adst[pos] = dd;
        Asrc[pos] = ssrc[slot];
        Aea[pos] = sea[slot];
    }
}

// ---------------- stage2: per-bucket counting sort -> indptr + edgedat ----------------
__global__ __launch_bounds__(256) void stage2_kernel(const int* __restrict__ bucketBase,
                                                     const int* __restrict__ Adst,
                                                     const int* __restrict__ Asrc,
                                                     const float* __restrict__ Aea,
                                                     int* __restrict__ indptr,
                                                     unsigned long long* __restrict__ edgedat) {
    __shared__ int cnt[256];
    __shared__ int dbase[256];
    __shared__ int wsum[4];
    int tid = threadIdx.x;
    int b = blockIdx.x;
    int start = bucketBase[b], end = bucketBase[b + 1];
    cnt[tid] = 0;
    __syncthreads();
    for (int i = start + tid; i < end; i += 256) atomicAdd(&cnt[Adst[i] & 255], 1);
    __syncthreads();
    int v = cnt[tid];
    int excl = block_excl_scan_256(v, tid, wsum);
    dbase[tid] = excl;
    __syncthreads();
    int n = b * 256 + tid;
    if (n < NN) indptr[n] = start + excl;
    cnt[tid] = 0;          // reuse as per-dst cursor
    __syncthreads();
    for (int i = start + tid; i < end; i += 256) {
        int dl = Adst[i] & 255;
        int r = atomicAdd(&cnt[dl], 1);   // LDS returning atomic
        int pos = start + dbase[dl] + r;
        edgedat[pos] = (unsigned long long)(unsigned int)Asrc[i] |
                       ((unsigned long long)__float_as_uint(Aea[i]) << 32);
    }
}

// ---------------- per-head attention constants + ea mean ----------------
__global__ void prep_kernel(const float* __restrict__ We1, const float* __restrict__ ae1,
                            const float* __restrict__ We2, const float* __restrict__ ae2,
                            float* __restrict__ consts) {
    int lane = threadIdx.x;
    if (lane < 4) {
        float s = 0.f;
        for (int c = 0; c < 32; c++) s += We1[lane * 32 + c] * ae1[lane * 32 + c];
        consts[2 + lane] = s;
    } else if (lane == 4) {
        float s = 0.f;
        for (int c = 0; c < 32; c++) s += We2[c] * ae2[c];
        consts[6] = s;
    } else if (lane == 5) {
        consts[1] = consts[0] / (float)EE;
    }
}

// ---------------- fp32 tiled GEMM ----------------
template <int TM, int TN, int TK, int RM, int RN, bool BF16OUT>
__global__ __launch_bounds__(256) void gemm_kernel(const float* __restrict__ A,
                                                   const float* __restrict__ B,
                                                   void* __restrict__ Cv, int M, int K) {
    static_assert(TM * TN == 256 * RM * RN, "thread coverage");
    static_assert(RN % 2 == 0, "pairable");
    __shared__ float As[TK][TM + 4];
    __shared__ float Bs[TK][TN];
    int tid = threadIdx.x;
    int tx = tid % (TN / RN);
    int ty = tid / (TN / RN);
    int blockRow = blockIdx.x * TM;
    float acc[RM][RN];
    #pragma unroll
    for (int i = 0; i < RM; i++)
        #pragma unroll
        for (int j = 0; j < RN; j++) acc[i][j] = 0.f;

    for (int k0 = 0; k0 < K; k0 += TK) {
        #pragma unroll
        for (int l = 0; l < TM * TK; l += 256 * 4) {
            int ll = l + tid * 4;
            if (ll < TM * TK) {
                int r = ll / TK, kk = ll % TK;
                float4 v = make_float4(0.f, 0.f, 0.f, 0.f);
                int gr = blockRow + r;
                if (gr < M) v = *(const float4*)(A + (size_t)gr * K + k0 + kk);
                As[kk + 0][r] = v.x;
                As[kk + 1][r] = v.y;
                As[kk + 2][r] = v.z;
                As[kk + 3][r] = v.w;
            }
        }
        #pragma unroll
        for (int l = 0; l < TK * TN; l += 256 * 4) {
            int ll = l + tid * 4;
            if (ll < TK * TN) {
                int kk = ll / TN, c = ll % TN;
                *(float4*)&Bs[kk][c] = *(const float4*)(B + (size_t)(k0 + kk) * TN + c);
            }
        }
        __syncthreads();
        #pragma unroll
        for (int k = 0; k < TK; k++) {
            float af[RM], bf[RN];
            #pragma unroll
            for (int i = 0; i < RM; i++) af[i] = As[k][ty * RM + i];
            #pragma unroll
            for (int j = 0; j < RN; j++) bf[j] = Bs[k][tx * RN + j];
            #pragma unroll
            for (int i = 0; i < RM; i++)
                #pragma unroll
                for (int j = 0; j < RN; j++) acc[i][j] += af[i] * bf[j];
        }
        __syncthreads();
    }
    #pragma unroll
    for (int i = 0; i < RM; i++) {
        int gr = blockRow + ty * RM + i;
        if (gr < M) {
            if (BF16OUT) {
                unsigned short* C = (unsigned short*)Cv;
                #pragma unroll
                for (int j = 0; j < RN; j += 2) {
                    unsigned int pk = (unsigned int)f2bf(acc[i][j]) |
                                      ((unsigned int)f2bf(acc[i][j + 1]) << 16);
                    *(unsigned int*)(C + (size_t)gr * TN + tx * RN + j) = pk;
                }
            } else {
                float* C = (float*)Cv;
                #pragma unroll
                for (int j = 0; j < RN; j++) C[(size_t)gr * TN + tx * RN + j] = acc[i][j];
            }
        }
    }
}

// ---------------- attention logits per node (bf16 inputs) ----------------
__global__ void al1_kernel(const unsigned short* __restrict__ xs1b, const float* __restrict__ as1,
                           const float* __restrict__ ad1, float* __restrict__ als,
                           float* __restrict__ ald) {
    int t = blockIdx.x * 256 + threadIdx.x;
    if (t >= NN * 4) return;
    int h = t & 3;
    const unsigned int* xp = (const unsigned int*)(xs1b + (size_t)t * 32);
    const float* ap = as1 + h * 32;
    const float* dp = ad1 + h * 32;
    float s = 0.f, d = 0.f;
    #pragma unroll
    for (int q = 0; q < 16; q++) {
        float2 v = bf2f2(xp[q]);
        s += v.x * ap[q * 2] + v.y * ap[q * 2 + 1];
        d += v.x * dp[q * 2] + v.y * dp[q * 2 + 1];
    }
    als[t] = s;
    ald[t] = d;
}

__global__ void al2_kernel(const unsigned short* __restrict__ xs2b, const float* __restrict__ as2,
                           const float* __restrict__ ad2, float* __restrict__ als,
                           float* __restrict__ ald) {
    int t = blockIdx.x * 256 + threadIdx.x;
    if (t >= NN) return;
    const unsigned int* xp = (const unsigned int*)(xs2b + (size_t)t * 32);
    float s = 0.f, d = 0.f;
    #pragma unroll
    for (int q = 0; q < 16; q++) {
        float2 v = bf2f2(xp[q]);
        s += v.x * as2[q * 2] + v.y * as2[q * 2 + 1];
        d += v.x * ad2[q * 2] + v.y * ad2[q * 2 + 1];
    }
    als[t] = s;
    ald[t] = d;
}

// ---------------- conv1 aggregation: one wave per dst node (H=4, F=128, bf16 gather) ----------------
__global__ __launch_bounds__(256) void gat1_agg(
    const unsigned short* __restrict__ xs1b, const float* __restrict__ als,
    const float* __restrict__ ald, const unsigned long long* __restrict__ edgedat,
    const int* __restrict__ indptr, const float* __restrict__ consts,
    const float* __restrict__ b1, const float* __restrict__ g1,
    const float* __restrict__ be1, float* __restrict__ h1out) {
    __shared__ float exbuf[4][CAP1 * 4];
    __shared__ int srcbuf[4][CAP1];
    int wv = threadIdx.x >> 6;
    int lane = threadIdx.x & 63;
    int n = blockIdx.x * 4 + wv;   // grid exact: NN % 4 == 0
    int start = indptr[n];
    int deg = indptr[n + 1] - start;
    float ea_mean = consts[1];
    float ce[4] = {consts[2], consts[3], consts[4], consts[5]};
    float4 a4d = *(const float4*)(ald + (size_t)n * 4);
    float aldh[4] = {a4d.x, a4d.y, a4d.z, a4d.w};
    float4 a4s = *(const float4*)(als + (size_t)n * 4);
    float alsn[4] = {a4s.x, a4s.y, a4s.z, a4s.w};
    float asl[4], mx[4];
    #pragma unroll
    for (int h = 0; h < 4; h++) {
        float a = lrelu(alsn[h] + aldh[h] + ea_mean * ce[h]);
        asl[h] = a;
        mx[h] = a;
    }
    const unsigned long long* edp = edgedat + start;
    for (int i = lane; i < deg; i += 64) {
        int s; float eav;
        unpack_edge(edp[i], s, eav);
        float4 v4 = *(const float4*)(als + (size_t)s * 4);
        float alv[4] = {v4.x, v4.y, v4.z, v4.w};
        bool st = (i < CAP1);
        if (st) srcbuf[wv][i] = s;
        #pragma unroll
        for (int h = 0; h < 4; h++) {
            float a = lrelu(alv[h] + aldh[h] + eav * ce[h]);
            if (st) exbuf[wv][i * 4 + h] = a;
            mx[h] = fmaxf(mx[h], a);
        }
    }
    #pragma unroll
    for (int h = 0; h < 4; h++)
        for (int off = 32; off > 0; off >>= 1) mx[h] = fmaxf(mx[h], __shfl_xor(mx[h], off));
    float sm[4] = {0.f, 0.f, 0.f, 0.f};
    for (int i = lane; i < deg; i += 64) {
        if (i < CAP1) {
            #pragma unroll
            for (int h = 0; h < 4; h++) {
                float exv = __expf(exbuf[wv][i * 4 + h] - mx[h]);
                exbuf[wv][i * 4 + h] = exv;
                sm[h] += exv;
            }
        } else {
            int s; float eav;
            unpack_edge(edp[i], s, eav);
            float4 v4 = *(const float4*)(als + (size_t)s * 4);
            float alv[4] = {v4.x, v4.y, v4.z, v4.w};
            #pragma unroll
            for (int h = 0; h < 4; h++) {
                float a = lrelu(alv[h] + aldh[h] + eav * ce[h]);
                sm[h] += __expf(a - mx[h]);
            }
        }
    }
    #pragma unroll
    for (int h = 0; h < 4; h++)
        for (int off = 32; off > 0; off >>= 1) sm[h] += __shfl_xor(sm[h], off);
    float inv[4];
    #pragma unroll
    for (int h = 0; h < 4; h++) inv[h] = 1.0f / (sm[h] + __expf(asl[h] - mx[h]) + 1e-16f);
    int c = lane * 2;
    int h = lane >> 4;
    float winv = inv[h];
    float wsl = __expf(asl[h] - mx[h]) * winv;
    float2 vself = bf2f2(*(const unsigned int*)(xs1b + (size_t)n * HC + c));
    float accx = vself.x * wsl, accy = vself.y * wsl;
    int m = deg < CAP1 ? deg : CAP1;
    int i = 0;
    for (; i + 4 <= m; i += 4) {
        float w0 = exbuf[wv][(i + 0) * 4 + h] * winv;
        float w1 = exbuf[wv][(i + 1) * 4 + h] * winv;
        float w2 = exbuf[wv][(i + 2) * 4 + h] * winv;
        float w3 = exbuf[wv][(i + 3) * 4 + h] * winv;
        int s0 = srcbuf[wv][i + 0], s1 = srcbuf[wv][i + 1];
        int s2 = srcbuf[wv][i + 2], s3 = srcbuf[wv][i + 3];
        float2 v0 = bf2f2(*(const unsigned int*)(xs1b + (size_t)s0 * HC + c));
        float2 v1 = bf2f2(*(const unsigned int*)(xs1b + (size_t)s1 * HC + c));
        float2 v2 = bf2f2(*(const unsigned int*)(xs1b + (size_t)s2 * HC + c));
        float2 v3 = bf2f2(*(const unsigned int*)(xs1b + (size_t)s3 * HC + c));
        accx += v0.x * w0; accy += v0.y * w0;
        accx += v1.x * w1; accy += v1.y * w1;
        accx += v2.x * w2; accy += v2.y * w2;
        accx += v3.x * w3; accy += v3.y * w3;
    }
    for (; i < m; i++) {
        float w0 = exbuf[wv][i * 4 + h] * winv;
        int s0 = srcbuf[wv][i];
        float2 v0 = bf2f2(*(const unsigned int*)(xs1b + (size_t)s0 * HC + c));
        accx += v0.x * w0; accy += v0.y * w0;
    }
    for (; i < deg; i++) {  // spill fallback
        int s; float eav;
        unpack_edge(edp[i], s, eav);
        float a = lrelu(als[(size_t)s * 4 + h] + aldh[h] + eav * ce[h]);
        float w0 = __expf(a - mx[h]) * winv;
        float2 v0 = bf2f2(*(const unsigned int*)(xs1b + (size_t)s * HC + c));
        accx += v0.x * w0; accy += v0.y * w0;
    }
    float o0 = accx + b1[c];
    float o1 = accy + b1[c + 1];
    o0 = o0 * (g1[c] * BN_RS) + be1[c];
    o1 = o1 * (g1[c + 1] * BN_RS) + be1[c + 1];
    o0 = elu(o0);
    o1 = elu(o1);
    *(float2*)(h1out + (size_t)n * HC + c) = make_float2(o0, o1);
}

// ---------------- conv2 aggregation + fused MLP heads ----------------
__global__ __launch_bounds__(256) void gat2_agg(
    const unsigned short* __restrict__ xs2b, const float* __restrict__ als,
    const float* __restrict__ ald, const unsigned long long* __restrict__ edgedat,
    const int* __restrict__ indptr, const float* __restrict__ consts,
    const float* __restrict__ b2, const float* __restrict__ g2, const float* __restrict__ be2,
    const float* __restrict__ Wc1, const float* __restrict__ bc1,
    const float* __restrict__ Wc2, const float* __restrict__ bc2,
    const float* __restrict__ Wr1, const float* __restrict__ br1,
    const float* __restrict__ Wr2, const float* __restrict__ br2,
    float* __restrict__ hout, float* __restrict__ cls, float* __restrict__ reg) {
    __shared__ float exbuf[4][CAP2];
    __shared__ int srcbuf[4][CAP2];
    __shared__ float hbuf[4][32];
    int wv = threadIdx.x >> 6;
    int lane = threadIdx.x & 63;
    int n = blockIdx.x * 4 + wv;
    int start = indptr[n];
    int deg = indptr[n + 1] - start;
    float ea_mean = consts[1];
    float ce = consts[6];
    float aldn = ald[n];
    float a0 = lrelu(als[n] + aldn + ea_mean * ce);
    float mx = a0;
    const unsigned long long* edp = edgedat + start;
    for (int i = lane; i < deg; i += 64) {
        int s; float eav;
        unpack_edge(edp[i], s, eav);
        float a = lrelu(als[s] + aldn + eav * ce);
        if (i < CAP2) { srcbuf[wv][i] = s; exbuf[wv][i] = a; }
        mx = fmaxf(mx, a);
    }
    for (int off = 32; off > 0; off >>= 1) mx = fmaxf(mx, __shfl_xor(mx, off));
    float sm = 0.f;
    for (int i = lane; i < deg; i += 64) {
        if (i < CAP2) {
            float exv = __expf(exbuf[wv][i] - mx);
            exbuf[wv][i] = exv;
            sm += exv;
        } else {
            int s; float eav;
            unpack_edge(edp[i], s, eav);
            float a = lrelu(als[s] + aldn + eav * ce);
            sm += __expf(a - mx);
        }
    }
    for (int off = 32; off > 0; off >>= 1) sm += __shfl_xor(sm, off);
    float invd = 1.0f / (sm + __expf(a0 - mx) + 1e-16f);
    int quarter = lane >> 4;
    int cl = lane & 15;
    int c = cl * 2;
    float accx = 0.f, accy = 0.f;
    if (quarter == 0) {
        float2 vs = bf2f2(*(const unsigned int*)(xs2b + (size_t)n * CD + c));
        float wsl = __expf(a0 - mx) * invd;
        accx = vs.x * wsl; accy = vs.y * wsl;
    }
    int m = deg < CAP2 ? deg : CAP2;
    for (int i = quarter; i < m; i += 4) {
        float w0 = exbuf[wv][i] * invd;
        int s0 = srcbuf[wv][i];
        float2 v0 = bf2f2(*(const unsigned int*)(xs2b + (size_t)s0 * CD + c));
        accx += v0.x * w0; accy += v0.y * w0;
    }
    for (int i = CAP2 + quarter; i < deg; i += 4) {
        int s; float eav;
        unpack_edge(edp[i], s, eav);
        float a = lrelu(als[s] + aldn + eav * ce);
        float w0 = __expf(a - mx) * invd;
        float2 v0 = bf2f2(*(const unsigned int*)(xs2b + (size_t)s * CD + c));
        accx += v0.x * w0; accy += v0.y * w0;
    }
    accx += __shfl_xor(accx, 16); accy += __shfl_xor(accy, 16);
    accx += __shfl_xor(accx, 32); accy += __shfl_xor(accy, 32);
    if (lane < 16) {
        float o0 = accx + b2[c];
        float o1 = accy + b2[c + 1];
        o0 = o0 * (g2[c] * BN_RS) + be2[c];
        o1 = o1 * (g2[c + 1] * BN_RS) + be2[c + 1];
        o0 = elu(o0);
        o1 = elu(o1);
        hbuf[wv][c] = o0;
        hbuf[wv][c + 1] = o1;
        *(float2*)(hout + (size_t)n * CD + c) = make_float2(o0, o1);
    }
    __syncthreads();
    float r0 = 0.f, r1 = 0.f;
    if (lane < 32) {
        int j = lane & 15;
        bool iscls = lane < 16;
        float s = iscls ? bc1[j] : br1[j];
        #pragma unroll
        for (int cc = 0; cc < 32; cc++) {
            float w = iscls ? Wc1[cc * 16 + j] : Wr1[cc * 16 + j];
            s += hbuf[wv][cc] * w;
        }
        s = fmaxf(s, 0.f);
        if (iscls) { r0 = s * Wc2[j * 2]; r1 = s * Wc2[j * 2 + 1]; }
        else       { r0 = s * Wr2[j]; }
    }
    #pragma unroll
    for (int off = 1; off < 16; off <<= 1) {
        r0 += __shfl_xor(r0, off);
        r1 += __shfl_xor(r1, off);
    }
    if (lane == 0)  *(float2*)(cls + (size_t)n * 2) = make_float2(r0 + bc2[0], r1 + bc2[1]);
    if (lane == 16) reg[n] = r0 + br2[0];
}

// ---------------- launch ----------------
extern "C" void kernel_launch(void* const* d_in, const int* in_sizes, int n_in,
                              void* d_out, int out_size, void* d_ws, size_t ws_size,
                              hipStream_t stream) {
    const float* x   = (const float*)d_in[0];
    const int*   ei  = (const int*)d_in[1];
    const float* ea  = (const float*)d_in[2];
    const float* W1  = (const float*)d_in[3];
    const float* as1 = (const float*)d_in[4];
    const float* ad1 = (const float*)d_in[5];
    const float* We1 = (const float*)d_in[6];
    const float* ae1 = (const float*)d_in[7];
    const float* b1  = (const float*)d_in[8];
    const float* g1  = (const float*)d_in[9];
    const float* be1 = (const float*)d_in[10];
    const float* W2  = (const float*)d_in[11];
    const float* as2 = (const float*)d_in[12];
    const float* ad2 = (const float*)d_in[13];
    const float* We2 = (const float*)d_in[14];
    const float* ae2 = (const float*)d_in[15];
    const float* b2  = (const float*)d_in[16];
    const float* g2  = (const float*)d_in[17];
    const float* be2 = (const float*)d_in[18];
    const float* Wc1 = (const float*)d_in[19];
    const float* bc1 = (const float*)d_in[20];
    const float* Wc2 = (const float*)d_in[21];
    const float* bc2 = (const float*)d_in[22];
    const float* Wr1 = (const float*)d_in[23];
    const float* br1 = (const float*)d_in[24];
    const float* Wr2 = (const float*)d_in[25];
    const float* br2 = (const float*)d_in[26];

    char* ws = (char*)d_ws;
    unsigned short* xs1b = (unsigned short*)(ws + 0);          // N*128 bf16 = 12.8 MB
    float* h1            = (float*)(ws + 12800000);            // N*128 f32 = 25.6 MB
    // staging arrays live inside h1's region (consumed by stage2 before gat1 writes h1)
    int*   Adst          = (int*)(ws + 12800000);              // E = 6.4 MB
    int*   Asrc          = (int*)(ws + 19200000);              // E = 6.4 MB
    float* Aea           = (float*)(ws + 25600000);            // E = 6.4 MB (ends 32.0 MB < 38.4)
    unsigned short* xs2b = (unsigned short*)(ws + 38400000);   // N*32 bf16 = 3.2 MB
    float* als1          = (float*)(ws + 41600000);            // N*4
    float* ald1          = (float*)(ws + 42400000);            // N*4
    float* als2          = (float*)(ws + 43200000);            // N
    float* ald2          = (float*)(ws + 43400000);            // N
    float* consts        = (float*)(ws + 43600000);            // 8 floats
    int*   bucketHist    = (int*)(ws + 43600128);              // 196
    int*   bucketBase    = (int*)(ws + 43601024);              // 197
    int*   bucketCursor  = (int*)(ws + 43601920);              // 196
    int*   indptr        = (int*)(ws + 43602816);              // N+1 (ends 43802820)
    unsigned long long* edgedat = (unsigned long long*)(ws + 43802824);  // E*8 = 12.8 MB (ends ~56.6 MB)

    float* out_cls = (float*)d_out;            // [N,2]
    float* out_reg = out_cls + 2 * NN;         // [N]
    float* out_h   = out_cls + 3 * NN;         // [N,32]

    hipMemsetAsync(bucketHist, 0, NBKT * sizeof(int), stream);
    hipMemsetAsync(consts, 0, 8 * sizeof(float), stream);

    // CSR build: no global returning atomics on the critical path
    hist_kernel<<<256, 256, 0, stream>>>(ei, ea, bucketHist, consts);
    bucket_scan<<<1, 256, 0, stream>>>(bucketHist, bucketBase, bucketCursor, indptr);
    stage1_kernel<<<S1_B, 256, 0, stream>>>(ei, ea, bucketCursor, Adst, Asrc, Aea);
    stage2_kernel<<<NBKT, 256, 0, stream>>>(bucketBase, Adst, Asrc, Aea, indptr, edgedat);
    prep_kernel<<<1, 64, 0, stream>>>(We1, ae1, We2, ae2, consts);

    // conv1
    gemm_kernel<64, 128, 32, 4, 8, true><<<(NN + 63) / 64, 256, 0, stream>>>(x, W1, xs1b, NN, IN_DIM);
    al1_kernel<<<(NN * 4 + 255) / 256, 256, 0, stream>>>(xs1b, as1, ad1, als1, ald1);
    gat1_agg<<<NN / 4, 256, 0, stream>>>(xs1b, als1, ald1, edgedat, indptr, consts,
                                         b1, g1, be1, h1);
    // conv2
    gemm_kernel<128, 32, 32, 8, 2, true><<<(NN + 127) / 128, 256, 0, stream>>>(h1, W2, xs2b, NN, HC);
    al2_kernel<<<(NN + 255) / 256, 256, 0, stream>>>(xs2b, as2, ad2, als2, ald2);
    gat2_agg<<<NN / 4, 256, 0, stream>>>(xs2b, als2, ald2, edgedat, indptr, consts,
                                         b2, g2, be2, Wc1, bc1, Wc2, bc2,
                                         Wr1, br1, Wr2, br2, out_h, out_cls, out_reg);
}

// Round 8
// 408.743 us; speedup vs baseline: 1.2431x; 1.0923x over previous
//
#include <hip/hip_runtime.h>
#include <cstdint>
#include <cstddef>

// ---------------- problem constants ----------------
#define NN 50000
#define EE 1600000
#define IN_DIM 256
#define HC 128      // HEADS*C
#define CD 32       // C
#define BN_RS 0.9999950000374997f  // 1/sqrt(1+1e-5)

#define CAP1 128
#define CAP2 128
#define NBKT 196        // ceil(NN/256) buckets of 256 dst nodes
#define S1_B 782        // (EE+2047)/2048

typedef __attribute__((ext_vector_type(8))) short short8;   // 8 bf16 (bit pattern)
typedef __attribute__((ext_vector_type(4))) float f32x4;

// ---------------- small helpers ----------------
__device__ __forceinline__ float lrelu(float a) { return a > 0.f ? a : 0.2f * a; }
__device__ __forceinline__ float elu(float a) { return a > 0.f ? a : (__expf(a) - 1.f); }

__device__ __forceinline__ unsigned short f2bf(float f) {
    unsigned int u = __float_as_uint(f);
    unsigned int r = (u + 0x7FFFu + ((u >> 16) & 1u)) >> 16;
    return (unsigned short)r;
}
__device__ __forceinline__ float bf2f(unsigned short b) {
    return __uint_as_float(((unsigned int)b) << 16);
}
__device__ __forceinline__ float2 bf2f2(unsigned int p) {
    float2 r;
    r.x = __uint_as_float(p << 16);
    r.y = __uint_as_float(p & 0xFFFF0000u);
    return r;
}
__device__ __forceinline__ void unpack_edge(unsigned long long p, int& s, float& eav) {
    s = (int)(unsigned int)(p & 0xFFFFFFFFull);
    eav = __uint_as_float((unsigned int)(p >> 32));
}

// 256-thread exclusive scan (ONE internal barrier; all 256 must call)
__device__ __forceinline__ int block_excl_scan_256(int v, int tid, int* wsum) {
    int lane = tid & 63, wv = tid >> 6;
    int x = v;
    #pragma unroll
    for (int off = 1; off < 64; off <<= 1) {
        int y = __shfl_up(x, off);
        if (lane >= off) x += y;
    }
    if (lane == 63) wsum[wv] = x;
    __syncthreads();
    int wpre = 0;
    #pragma unroll
    for (int w = 0; w < 4; w++)
        if (w < wv) wpre += wsum[w];
    return wpre + x - v;
}

// ---------------- hist: 196-bin bucket histogram (LDS) + ea sum ----------------
__global__ __launch_bounds__(256) void hist_kernel(const int* __restrict__ ei,
                                                   const float* __restrict__ ea,
                                                   int* __restrict__ bucketHist,
                                                   float* __restrict__ easum) {
    __shared__ int h[256];
    int tid = threadIdx.x;
    h[tid] = 0;
    __syncthreads();
    float s = 0.f;
    for (int i = blockIdx.x * 256 + tid; i < EE; i += gridDim.x * 256) {
        atomicAdd(&h[ei[EE + i] >> 8], 1);
        s += ea[i];
    }
    __syncthreads();
    if (tid < NBKT && h[tid] > 0) atomicAdd(&bucketHist[tid], h[tid]);
    #pragma unroll
    for (int off = 32; off > 0; off >>= 1) s += __shfl_xor(s, off);
    if ((tid & 63) == 0) atomicAdd(easum, s);
}

// ---------------- bucket scan: bases + cursors + tail sentinels ----------------
__global__ void bucket_scan(const int* __restrict__ bucketHist,
                            int* __restrict__ bucketBase,
                            int* __restrict__ bucketCursor,
                            int* __restrict__ indptr) {
    __shared__ int wsum[4];
    int tid = threadIdx.x;  // 256
    int v = (tid < NBKT) ? bucketHist[tid] : 0;
    int excl = block_excl_scan_256(v, tid, wsum);
    if (tid <= NBKT) bucketBase[tid] = (tid == NBKT) ? EE : excl;
    if (tid < NBKT) bucketCursor[tid] = excl;
    if (tid == 0) indptr[NN] = EE;
}

// ---------------- stage1: LDS bin by bucket, block-reserve, copy-out ----------------
__global__ __launch_bounds__(256) void stage1_kernel(const int* __restrict__ ei,
                                                     const float* __restrict__ ea,
                                                     int* __restrict__ bucketCursor,
                                                     int* __restrict__ Adst,
                                                     int* __restrict__ Asrc,
                                                     float* __restrict__ Aea) {
    __shared__ int cnt[256];
    __shared__ int basel[256];
    __shared__ int gbase[256];
    __shared__ int wsum[4];
    __shared__ int sdst[2048];
    __shared__ int ssrc[2048];
    __shared__ float sea[2048];
    int tid = threadIdx.x;
    int base = blockIdx.x * 2048;
    cnt[tid] = 0;
    __syncthreads();
    int d[8], s[8], r[8], bk[8];
    float e[8];
    #pragma unroll
    for (int k = 0; k < 8; k++) {
        int i = base + k * 256 + tid;
        if (i < EE) {
            d[k] = ei[EE + i];
            s[k] = ei[i];
            e[k] = ea[i];
            bk[k] = d[k] >> 8;
            r[k] = atomicAdd(&cnt[bk[k]], 1);   // LDS returning atomic: cheap
        } else d[k] = -1;
    }
    __syncthreads();
    int v = cnt[tid];
    int excl = block_excl_scan_256(v, tid, wsum);
    basel[tid] = excl;
    if (tid < NBKT) gbase[tid] = atomicAdd(&bucketCursor[tid], v);
    __syncthreads();
    #pragma unroll
    for (int k = 0; k < 8; k++) {
        if (d[k] >= 0) {
            int slot = basel[bk[k]] + r[k];
            sdst[slot] = d[k];
            ssrc[slot] = s[k];
            sea[slot] = e[k];
        }
    }
    __syncthreads();
    int total = basel[255] + cnt[255];
    for (int slot = tid; slot < total; slot += 256) {
        int dd = sdst[slot];
        int b = dd >> 8;
        int pos = gbase[b] + (slot - basel[b]);
        Adst[pos] = dd;
        Asrc[pos] = ssrc[slot];
        Aea[pos] = sea[slot];
    }
}

// ---------------- stage2: per-bucket counting sort -> indptr + edgedat ----------------
__global__ __launch_bounds__(256) void stage2_kernel(const int* __restrict__ bucketBase,
                                                     const int* __restrict__ Adst,
                                                     const int* __restrict__ Asrc,
                                                     const float* __restrict__ Aea,
                                                     int* __restrict__ indptr,
                                                     unsigned long long* __restrict__ edgedat) {
    __shared__ int cnt[256];
    __shared__ int dbase[256];
    __shared__ int wsum[4];
    int tid = threadIdx.x;
    int b = blockIdx.x;
    int start = bucketBase[b], end = bucketBase[b + 1];
    cnt[tid] = 0;
    __syncthreads();
    for (int i = start + tid; i < end; i += 256) atomicAdd(&cnt[Adst[i] & 255], 1);
    __syncthreads();
    int v = cnt[tid];
    int excl = block_excl_scan_256(v, tid, wsum);
    dbase[tid] = excl;
    __syncthreads();
    int n = b * 256 + tid;
    if (n < NN) indptr[n] = start + excl;
    cnt[tid] = 0;          // reuse as per-dst cursor
    __syncthreads();
    for (int i = start + tid; i < end; i += 256) {
        int dl = Adst[i] & 255;
        int r = atomicAdd(&cnt[dl], 1);
        int pos = start + dbase[dl] + r;
        edgedat[pos] = (unsigned long long)(unsigned int)Asrc[i] |
                       ((unsigned long long)__float_as_uint(Aea[i]) << 32);
    }
}

// ---------------- per-head attention constants + ea mean ----------------
__global__ void prep_kernel(const float* __restrict__ We1, const float* __restrict__ ae1,
                            const float* __restrict__ We2, const float* __restrict__ ae2,
                            float* __restrict__ consts) {
    int lane = threadIdx.x;
    if (lane < 4) {
        float s = 0.f;
        for (int c = 0; c < 32; c++) s += We1[lane * 32 + c] * ae1[lane * 32 + c];
        consts[2 + lane] = s;
    } else if (lane == 4) {
        float s = 0.f;
        for (int c = 0; c < 32; c++) s += We2[c] * ae2[c];
        consts[6] = s;
    } else if (lane == 5) {
        consts[1] = consts[0] / (float)EE;
    }
}

// ---------------- prep W1 into MFMA B-fragment order, split hi/lo bf16 ----------------
// B-frag for (nt,kt): element j of lane l = W1[kt*32 + (l>>4)*8 + j][nt*16 + (l&15)]
// linear: ((nt*8 + kt)*64 + l)*8 + j
__global__ __launch_bounds__(256) void prep_w1_kernel(const float* __restrict__ W1,
                                                      unsigned short* __restrict__ Whi,
                                                      unsigned short* __restrict__ Wlo) {
    int t = blockIdx.x * 256 + threadIdx.x;   // 4096 threads: (nt,kt,lane)
    int lane = t & 63;
    int kt = (t >> 6) & 7;
    int nt = t >> 9;
    int kbase = kt * 32 + (lane >> 4) * 8;
    int col = nt * 16 + (lane & 15);
    size_t obase = (size_t)t * 8;
    #pragma unroll
    for (int j = 0; j < 8; j++) {
        float w = W1[(size_t)(kbase + j) * HC + col];
        unsigned short h = f2bf(w);
        float hf = bf2f(h);
        Whi[obase + j] = h;
        Wlo[obase + j] = f2bf(w - hf);
    }
}

// ---------------- gemm1 via MFMA split-bf16: xs1 = x @ W1 ----------------
// one wave per 16 rows; all 128 cols; K=256. D = Ahi*Bhi + Ahi*Blo + Alo*Bhi.
__global__ __launch_bounds__(64) void gemm1_mfma(const float* __restrict__ x,
                                                 const unsigned short* __restrict__ Whi,
                                                 const unsigned short* __restrict__ Wlo,
                                                 unsigned short* __restrict__ xs1b) {
    int lane = threadIdx.x;           // 64
    int row0 = blockIdx.x * 16;       // NN = 16 * 3125 exactly
    int m = lane & 15;
    int q = lane >> 4;
    f32x4 acc[8];
    #pragma unroll
    for (int nt = 0; nt < 8; nt++) acc[nt] = {0.f, 0.f, 0.f, 0.f};
    const float* xrow = x + (size_t)(row0 + m) * IN_DIM + q * 8;
    #pragma unroll
    for (int kt = 0; kt < 8; kt++) {
        float4 v0 = *(const float4*)(xrow + kt * 32);
        float4 v1 = *(const float4*)(xrow + kt * 32 + 4);
        float vv[8] = {v0.x, v0.y, v0.z, v0.w, v1.x, v1.y, v1.z, v1.w};
        short8 ahi, alo;
        #pragma unroll
        for (int j = 0; j < 8; j++) {
            unsigned short h = f2bf(vv[j]);
            ahi[j] = (short)h;
            alo[j] = (short)f2bf(vv[j] - bf2f(h));
        }
        #pragma unroll
        for (int nt = 0; nt < 8; nt++) {
            size_t fb = ((size_t)(nt * 8 + kt) * 64 + lane) * 8;
            short8 bhi = *(const short8*)(Whi + fb);
            short8 blo = *(const short8*)(Wlo + fb);
            acc[nt] = __builtin_amdgcn_mfma_f32_16x16x32_bf16(ahi, bhi, acc[nt], 0, 0, 0);
            acc[nt] = __builtin_amdgcn_mfma_f32_16x16x32_bf16(ahi, blo, acc[nt], 0, 0, 0);
            acc[nt] = __builtin_amdgcn_mfma_f32_16x16x32_bf16(alo, bhi, acc[nt], 0, 0, 0);
        }
    }
    // C/D layout: col = lane&15, row = (lane>>4)*4 + reg
    #pragma unroll
    for (int nt = 0; nt < 8; nt++) {
        #pragma unroll
        for (int reg = 0; reg < 4; reg++) {
            int row = row0 + q * 4 + reg;
            xs1b[(size_t)row * HC + nt * 16 + m] = f2bf(acc[nt][reg]);
        }
    }
}

// ---------------- fp32 tiled GEMM (gemm2) ----------------
template <int TM, int TN, int TK, int RM, int RN, bool BF16OUT>
__global__ __launch_bounds__(256) void gemm_kernel(const float* __restrict__ A,
                                                   const float* __restrict__ B,
                                                   void* __restrict__ Cv, int M, int K) {
    static_assert(TM * TN == 256 * RM * RN, "thread coverage");
    static_assert(RN % 2 == 0, "pairable");
    __shared__ float As[TK][TM + 4];
    __shared__ float Bs[TK][TN];
    int tid = threadIdx.x;
    int tx = tid % (TN / RN);
    int ty = tid / (TN / RN);
    int blockRow = blockIdx.x * TM;
    float acc[RM][RN];
    #pragma unroll
    for (int i = 0; i < RM; i++)
        #pragma unroll
        for (int j = 0; j < RN; j++) acc[i][j] = 0.f;

    for (int k0 = 0; k0 < K; k0 += TK) {
        #pragma unroll
        for (int l = 0; l < TM * TK; l += 256 * 4) {
            int ll = l + tid * 4;
            if (ll < TM * TK) {
                int r = ll / TK, kk = ll % TK;
                float4 v = make_float4(0.f, 0.f, 0.f, 0.f);
                int gr = blockRow + r;
                if (gr < M) v = *(const float4*)(A + (size_t)gr * K + k0 + kk);
                As[kk + 0][r] = v.x;
                As[kk + 1][r] = v.y;
                As[kk + 2][r] = v.z;
                As[kk + 3][r] = v.w;
            }
        }
        #pragma unroll
        for (int l = 0; l < TK * TN; l += 256 * 4) {
            int ll = l + tid * 4;
            if (ll < TK * TN) {
                int kk = ll / TN, c = ll % TN;
                *(float4*)&Bs[kk][c] = *(const float4*)(B + (size_t)(k0 + kk) * TN + c);
            }
        }
        __syncthreads();
        #pragma unroll
        for (int k = 0; k < TK; k++) {
            float af[RM], bf[RN];
            #pragma unroll
            for (int i = 0; i < RM; i++) af[i] = As[k][ty * RM + i];
            #pragma unroll
            for (int j = 0; j < RN; j++) bf[j] = Bs[k][tx * RN + j];
            #pragma unroll
            for (int i = 0; i < RM; i++)
                #pragma unroll
                for (int j = 0; j < RN; j++) acc[i][j] += af[i] * bf[j];
        }
        __syncthreads();
    }
    #pragma unroll
    for (int i = 0; i < RM; i++) {
        int gr = blockRow + ty * RM + i;
        if (gr < M) {
            if (BF16OUT) {
                unsigned short* C = (unsigned short*)Cv;
                #pragma unroll
                for (int j = 0; j < RN; j += 2) {
                    unsigned int pk = (unsigned int)f2bf(acc[i][j]) |
                                      ((unsigned int)f2bf(acc[i][j + 1]) << 16);
                    *(unsigned int*)(C + (size_t)gr * TN + tx * RN + j) = pk;
                }
            } else {
                float* C = (float*)Cv;
                #pragma unroll
                for (int j = 0; j < RN; j++) C[(size_t)gr * TN + tx * RN + j] = acc[i][j];
            }
        }
    }
}

// ---------------- attention logits per node (bf16 inputs) ----------------
__global__ void al1_kernel(const unsigned short* __restrict__ xs1b, const float* __restrict__ as1,
                           const float* __restrict__ ad1, float* __restrict__ als,
                           float* __restrict__ ald) {
    int t = blockIdx.x * 256 + threadIdx.x;
    if (t >= NN * 4) return;
    int h = t & 3;
    const unsigned int* xp = (const unsigned int*)(xs1b + (size_t)t * 32);
    const float* ap = as1 + h * 32;
    const float* dp = ad1 + h * 32;
    float s = 0.f, d = 0.f;
    #pragma unroll
    for (int q = 0; q < 16; q++) {
        float2 v = bf2f2(xp[q]);
        s += v.x * ap[q * 2] + v.y * ap[q * 2 + 1];
        d += v.x * dp[q * 2] + v.y * dp[q * 2 + 1];
    }
    als[t] = s;
    ald[t] = d;
}

__global__ void al2_kernel(const unsigned short* __restrict__ xs2b, const float* __restrict__ as2,
                           const float* __restrict__ ad2, float* __restrict__ als,
                           float* __restrict__ ald) {
    int t = blockIdx.x * 256 + threadIdx.x;
    if (t >= NN) return;
    const unsigned int* xp = (const unsigned int*)(xs2b + (size_t)t * 32);
    float s = 0.f, d = 0.f;
    #pragma unroll
    for (int q = 0; q < 16; q++) {
        float2 v = bf2f2(xp[q]);
        s += v.x * as2[q * 2] + v.y * as2[q * 2 + 1];
        d += v.x * ad2[q * 2] + v.y * ad2[q * 2 + 1];
    }
    als[t] = s;
    ald[t] = d;
}

// ---------------- conv1 aggregation: one wave per dst node (H=4, F=128, bf16 gather) ----------------
__global__ __launch_bounds__(256) void gat1_agg(
    const unsigned short* __restrict__ xs1b, const float* __restrict__ als,
    const float* __restrict__ ald, const unsigned long long* __restrict__ edgedat,
    const int* __restrict__ indptr, const float* __restrict__ consts,
    const float* __restrict__ b1, const float* __restrict__ g1,
    const float* __restrict__ be1, float* __restrict__ h1out) {
    __shared__ float exbuf[4][CAP1 * 4];
    __shared__ int srcbuf[4][CAP1];
    int wv = threadIdx.x >> 6;
    int lane = threadIdx.x & 63;
    int n = blockIdx.x * 4 + wv;
    int start = indptr[n];
    int deg = indptr[n + 1] - start;
    float ea_mean = consts[1];
    float ce[4] = {consts[2], consts[3], consts[4], consts[5]};
    float4 a4d = *(const float4*)(ald + (size_t)n * 4);
    float aldh[4] = {a4d.x, a4d.y, a4d.z, a4d.w};
    float4 a4s = *(const float4*)(als + (size_t)n * 4);
    float alsn[4] = {a4s.x, a4s.y, a4s.z, a4s.w};
    float asl[4], mx[4];
    #pragma unroll
    for (int h = 0; h < 4; h++) {
        float a = lrelu(alsn[h] + aldh[h] + ea_mean * ce[h]);
        asl[h] = a;
        mx[h] = a;
    }
    const unsigned long long* edp = edgedat + start;
    for (int i = lane; i < deg; i += 64) {
        int s; float eav;
        unpack_edge(edp[i], s, eav);
        float4 v4 = *(const float4*)(als + (size_t)s * 4);
        float alv[4] = {v4.x, v4.y, v4.z, v4.w};
        bool st = (i < CAP1);
        if (st) srcbuf[wv][i] = s;
        #pragma unroll
        for (int h = 0; h < 4; h++) {
            float a = lrelu(alv[h] + aldh[h] + eav * ce[h]);
            if (st) exbuf[wv][i * 4 + h] = a;
            mx[h] = fmaxf(mx[h], a);
        }
    }
    #pragma unroll
    for (int h = 0; h < 4; h++)
        for (int off = 32; off > 0; off >>= 1) mx[h] = fmaxf(mx[h], __shfl_xor(mx[h], off));
    float sm[4] = {0.f, 0.f, 0.f, 0.f};
    for (int i = lane; i < deg; i += 64) {
        if (i < CAP1) {
            #pragma unroll
            for (int h = 0; h < 4; h++) {
                float exv = __expf(exbuf[wv][i * 4 + h] - mx[h]);
                exbuf[wv][i * 4 + h] = exv;
                sm[h] += exv;
            }
        } else {
            int s; float eav;
            unpack_edge(edp[i], s, eav);
            float4 v4 = *(const float4*)(als + (size_t)s * 4);
            float alv[4] = {v4.x, v4.y, v4.z, v4.w};
            #pragma unroll
            for (int h = 0; h < 4; h++) {
                float a = lrelu(alv[h] + aldh[h] + eav * ce[h]);
                sm[h] += __expf(a - mx[h]);
            }
        }
    }
    #pragma unroll
    for (int h = 0; h < 4; h++)
        for (int off = 32; off > 0; off >>= 1) sm[h] += __shfl_xor(sm[h], off);
    float inv[4];
    #pragma unroll
    for (int h = 0; h < 4; h++) inv[h] = 1.0f / (sm[h] + __expf(asl[h] - mx[h]) + 1e-16f);
    int c = lane * 2;
    int h = lane >> 4;
    float winv = inv[h];
    float wsl = __expf(asl[h] - mx[h]) * winv;
    float2 vself = bf2f2(*(const unsigned int*)(xs1b + (size_t)n * HC + c));
    float accx = vself.x * wsl, accy = vself.y * wsl;
    int m = deg < CAP1 ? deg : CAP1;
    int i = 0;
    for (; i + 4 <= m; i += 4) {
        float w0 = exbuf[wv][(i + 0) * 4 + h] * winv;
        float w1 = exbuf[wv][(i + 1) * 4 + h] * winv;
        float w2 = exbuf[wv][(i + 2) * 4 + h] * winv;
        float w3 = exbuf[wv][(i + 3) * 4 + h] * winv;
        int s0 = srcbuf[wv][i + 0], s1 = srcbuf[wv][i + 1];
        int s2 = srcbuf[wv][i + 2], s3 = srcbuf[wv][i + 3];
        float2 v0 = bf2f2(*(const unsigned int*)(xs1b + (size_t)s0 * HC + c));
        float2 v1 = bf2f2(*(const unsigned int*)(xs1b + (size_t)s1 * HC + c));
        float2 v2 = bf2f2(*(const unsigned int*)(xs1b + (size_t)s2 * HC + c));
        float2 v3 = bf2f2(*(const unsigned int*)(xs1b + (size_t)s3 * HC + c));
        accx += v0.x * w0; accy += v0.y * w0;
        accx += v1.x * w1; accy += v1.y * w1;
        accx += v2.x * w2; accy += v2.y * w2;
        accx += v3.x * w3; accy += v3.y * w3;
    }
    for (; i < m; i++) {
        float w0 = exbuf[wv][i * 4 + h] * winv;
        int s0 = srcbuf[wv][i];
        float2 v0 = bf2f2(*(const unsigned int*)(xs1b + (size_t)s0 * HC + c));
        accx += v0.x * w0; accy += v0.y * w0;
    }
    for (; i < deg; i++) {  // spill fallback
        int s; float eav;
        unpack_edge(edp[i], s, eav);
        float a = lrelu(als[(size_t)s * 4 + h] + aldh[h] + eav * ce[h]);
        float w0 = __expf(a - mx[h]) * winv;
        float2 v0 = bf2f2(*(const unsigned int*)(xs1b + (size_t)s * HC + c));
        accx += v0.x * w0; accy += v0.y * w0;
    }
    float o0 = accx + b1[c];
    float o1 = accy + b1[c + 1];
    o0 = o0 * (g1[c] * BN_RS) + be1[c];
    o1 = o1 * (g1[c + 1] * BN_RS) + be1[c + 1];
    o0 = elu(o0);
    o1 = elu(o1);
    *(float2*)(h1out + (size_t)n * HC + c) = make_float2(o0, o1);
}

// ---------------- conv2 aggregation + fused MLP heads ----------------
__global__ __launch_bounds__(256) void gat2_agg(
    const unsigned short* __restrict__ xs2b, const float* __restrict__ als,
    const float* __restrict__ ald, const unsigned long long* __restrict__ edgedat,
    const int* __restrict__ indptr, const float* __restrict__ consts,
    const float* __restrict__ b2, const float* __restrict__ g2, const float* __restrict__ be2,
    const float* __restrict__ Wc1, const float* __restrict__ bc1,
    const float* __restrict__ Wc2, const float* __restrict__ bc2,
    const float* __restrict__ Wr1, const float* __restrict__ br1,
    const float* __restrict__ Wr2, const float* __restrict__ br2,
    float* __restrict__ hout, float* __restrict__ cls, float* __restrict__ reg) {
    __shared__ float exbuf[4][CAP2];
    __shared__ int srcbuf[4][CAP2];
    __shared__ float hbuf[4][32];
    int wv = threadIdx.x >> 6;
    int lane = threadIdx.x & 63;
    int n = blockIdx.x * 4 + wv;
    int start = indptr[n];
    int deg = indptr[n + 1] - start;
    float ea_mean = consts[1];
    float ce = consts[6];
    float aldn = ald[n];
    float a0 = lrelu(als[n] + aldn + ea_mean * ce);
    float mx = a0;
    const unsigned long long* edp = edgedat + start;
    for (int i = lane; i < deg; i += 64) {
        int s; float eav;
        unpack_edge(edp[i], s, eav);
        float a = lrelu(als[s] + aldn + eav * ce);
        if (i < CAP2) { srcbuf[wv][i] = s; exbuf[wv][i] = a; }
        mx = fmaxf(mx, a);
    }
    for (int off = 32; off > 0; off >>= 1) mx = fmaxf(mx, __shfl_xor(mx, off));
    float sm = 0.f;
    for (int i = lane; i < deg; i += 64) {
        if (i < CAP2) {
            float exv = __expf(exbuf[wv][i] - mx);
            exbuf[wv][i] = exv;
            sm += exv;
        } else {
            int s; float eav;
            unpack_edge(edp[i], s, eav);
            float a = lrelu(als[s] + aldn + eav * ce);
            sm += __expf(a - mx);
        }
    }
    for (int off = 32; off > 0; off >>= 1) sm += __shfl_xor(sm, off);
    float invd = 1.0f / (sm + __expf(a0 - mx) + 1e-16f);
    int quarter = lane >> 4;
    int cl = lane & 15;
    int c = cl * 2;
    float accx = 0.f, accy = 0.f;
    if (quarter == 0) {
        float2 vs = bf2f2(*(const unsigned int*)(xs2b + (size_t)n * CD + c));
        float wsl = __expf(a0 - mx) * invd;
        accx = vs.x * wsl; accy = vs.y * wsl;
    }
    int m = deg < CAP2 ? deg : CAP2;
    for (int i = quarter; i < m; i += 4) {
        float w0 = exbuf[wv][i] * invd;
        int s0 = srcbuf[wv][i];
        float2 v0 = bf2f2(*(const unsigned int*)(xs2b + (size_t)s0 * CD + c));
        accx += v0.x * w0; accy += v0.y * w0;
    }
    for (int i = CAP2 + quarter; i < deg; i += 4) {
        int s; float eav;
        unpack_edge(edp[i], s, eav);
        float a = lrelu(als[s] + aldn + eav * ce);
        float w0 = __expf(a - mx) * invd;
        float2 v0 = bf2f2(*(const unsigned int*)(xs2b + (size_t)s * CD + c));
        accx += v0.x * w0; accy += v0.y * w0;
    }
    accx += __shfl_xor(accx, 16); accy += __shfl_xor(accy, 16);
    accx += __shfl_xor(accx, 32); accy += __shfl_xor(accy, 32);
    if (lane < 16) {
        float o0 = accx + b2[c];
        float o1 = accy + b2[c + 1];
        o0 = o0 * (g2[c] * BN_RS) + be2[c];
        o1 = o1 * (g2[c + 1] * BN_RS) + be2[c + 1];
        o0 = elu(o0);
        o1 = elu(o1);
        hbuf[wv][c] = o0;
        hbuf[wv][c + 1] = o1;
        *(float2*)(hout + (size_t)n * CD + c) = make_float2(o0, o1);
    }
    __syncthreads();
    float r0 = 0.f, r1 = 0.f;
    if (lane < 32) {
        int j = lane & 15;
        bool iscls = lane < 16;
        float s = iscls ? bc1[j] : br1[j];
        #pragma unroll
        for (int cc = 0; cc < 32; cc++) {
            float w = iscls ? Wc1[cc * 16 + j] : Wr1[cc * 16 + j];
            s += hbuf[wv][cc] * w;
        }
        s = fmaxf(s, 0.f);
        if (iscls) { r0 = s * Wc2[j * 2]; r1 = s * Wc2[j * 2 + 1]; }
        else       { r0 = s * Wr2[j]; }
    }
    #pragma unroll
    for (int off = 1; off < 16; off <<= 1) {
        r0 += __shfl_xor(r0, off);
        r1 += __shfl_xor(r1, off);
    }
    if (lane == 0)  *(float2*)(cls + (size_t)n * 2) = make_float2(r0 + bc2[0], r1 + bc2[1]);
    if (lane == 16) reg[n] = r0 + br2[0];
}

// ---------------- launch ----------------
extern "C" void kernel_launch(void* const* d_in, const int* in_sizes, int n_in,
                              void* d_out, int out_size, void* d_ws, size_t ws_size,
                              hipStream_t stream) {
    const float* x   = (const float*)d_in[0];
    const int*   ei  = (const int*)d_in[1];
    const float* ea  = (const float*)d_in[2];
    const float* W1  = (const float*)d_in[3];
    const float* as1 = (const float*)d_in[4];
    const float* ad1 = (const float*)d_in[5];
    const float* We1 = (const float*)d_in[6];
    const float* ae1 = (const float*)d_in[7];
    const float* b1  = (const float*)d_in[8];
    const float* g1  = (const float*)d_in[9];
    const float* be1 = (const float*)d_in[10];
    const float* W2  = (const float*)d_in[11];
    const float* as2 = (const float*)d_in[12];
    const float* ad2 = (const float*)d_in[13];
    const float* We2 = (const float*)d_in[14];
    const float* ae2 = (const float*)d_in[15];
    const float* b2  = (const float*)d_in[16];
    const float* g2  = (const float*)d_in[17];
    const float* be2 = (const float*)d_in[18];
    const float* Wc1 = (const float*)d_in[19];
    const float* bc1 = (const float*)d_in[20];
    const float* Wc2 = (const float*)d_in[21];
    const float* bc2 = (const float*)d_in[22];
    const float* Wr1 = (const float*)d_in[23];
    const float* br1 = (const float*)d_in[24];
    const float* Wr2 = (const float*)d_in[25];
    const float* br2 = (const float*)d_in[26];

    char* ws = (char*)d_ws;
    unsigned short* xs1b = (unsigned short*)(ws + 0);          // N*128 bf16 = 12.8 MB
    float* h1            = (float*)(ws + 12800000);            // N*128 f32 = 25.6 MB
    // staging arrays alias h1 (consumed by stage2 before gat1 writes h1)
    int*   Adst          = (int*)(ws + 12800000);              // E = 6.4 MB
    int*   Asrc          = (int*)(ws + 19200000);              // E = 6.4 MB
    float* Aea           = (float*)(ws + 25600000);            // E = 6.4 MB (ends 32.0 MB)
    unsigned short* xs2b = (unsigned short*)(ws + 38400000);   // N*32 bf16 = 3.2 MB
    float* als1          = (float*)(ws + 41600000);            // N*4
    float* ald1          = (float*)(ws + 42400000);            // N*4
    float* als2          = (float*)(ws + 43200000);            // N
    float* ald2          = (float*)(ws + 43400000);            // N
    float* consts        = (float*)(ws + 43600000);            // 8 floats
    int*   bucketHist    = (int*)(ws + 43600128);              // 196
    int*   bucketBase    = (int*)(ws + 43601024);              // 197
    int*   bucketCursor  = (int*)(ws + 43601920);              // 196
    int*   indptr        = (int*)(ws + 43602816);              // N+1
    unsigned long long* edgedat = (unsigned long long*)(ws + 43802824);  // E*8 = 12.8 MB -> ends 56602824
    unsigned short* W1hi = (unsigned short*)(ws + 56602832);   // 32768 bf16 = 64 KB
    unsigned short* W1lo = (unsigned short*)(ws + 56668368);   // 64 KB (ends ~56.73 MB)

    float* out_cls = (float*)d_out;            // [N,2]
    float* out_reg = out_cls + 2 * NN;         // [N]
    float* out_h   = out_cls + 3 * NN;         // [N,32]

    hipMemsetAsync(bucketHist, 0, NBKT * sizeof(int), stream);
    hipMemsetAsync(consts, 0, 8 * sizeof(float), stream);

    // CSR build (no global returning atomics) + W1 prepack
    hist_kernel<<<256, 256, 0, stream>>>(ei, ea, bucketHist, consts);
    prep_w1_kernel<<<16, 256, 0, stream>>>(W1, W1hi, W1lo);
    bucket_scan<<<1, 256, 0, stream>>>(bucketHist, bucketBase, bucketCursor, indptr);
    stage1_kernel<<<S1_B, 256, 0, stream>>>(ei, ea, bucketCursor, Adst, Asrc, Aea);
    stage2_kernel<<<NBKT, 256, 0, stream>>>(bucketBase, Adst, Asrc, Aea, indptr, edgedat);
    prep_kernel<<<1, 64, 0, stream>>>(We1, ae1, We2, ae2, consts);

    // conv1: MFMA split-bf16 GEMM
    gemm1_mfma<<<NN / 16, 64, 0, stream>>>(x, W1hi, W1lo, xs1b);
    al1_kernel<<<(NN * 4 + 255) / 256, 256, 0, stream>>>(xs1b, as1, ad1, als1, ald1);
    gat1_agg<<<NN / 4, 256, 0, stream>>>(xs1b, als1, ald1, edgedat, indptr, consts,
                                         b1, g1, be1, h1);
    // conv2
    gemm_kernel<128, 32, 32, 8, 2, true><<<(NN + 127) / 128, 256, 0, stream>>>(h1, W2, xs2b, NN, HC);
    al2_kernel<<<(NN + 255) / 256, 256, 0, stream>>>(xs2b, as2, ad2, als2, ald2);
    gat2_agg<<<NN / 4, 256, 0, stream>>>(xs2b, als2, ald2, edgedat, indptr, consts,
                                         b2, g2, be2, Wc1, bc1, Wc2, bc2,
                                         Wr1, br1, Wr2, br2, out_h, out_cls, out_reg);
}

// Round 9
// 404.534 us; speedup vs baseline: 1.2561x; 1.0104x over previous
//
#include <hip/hip_runtime.h>
#include <cstdint>
#include <cstddef>

// ---------------- problem constants ----------------
#define NN 50000
#define EE 1600000
#define IN_DIM 256
#define HC 128      // HEADS*C
#define CD 32       // C
#define BN_RS 0.9999950000374997f  // 1/sqrt(1+1e-5)

#define CAP1 128
#define CAP2 128
#define NBKT 196        // ceil(NN/256) buckets of 256 dst nodes
#define S1_B 782        // (EE+2047)/2048

typedef __attribute__((ext_vector_type(8))) short short8;   // 8 bf16 (bit pattern)
typedef __attribute__((ext_vector_type(4))) float f32x4;

// ---------------- small helpers ----------------
__device__ __forceinline__ float lrelu(float a) { return a > 0.f ? a : 0.2f * a; }
__device__ __forceinline__ float elu(float a) { return a > 0.f ? a : (__expf(a) - 1.f); }

__device__ __forceinline__ unsigned short f2bf(float f) {
    unsigned int u = __float_as_uint(f);
    unsigned int r = (u + 0x7FFFu + ((u >> 16) & 1u)) >> 16;
    return (unsigned short)r;
}
__device__ __forceinline__ float bf2f(unsigned short b) {
    return __uint_as_float(((unsigned int)b) << 16);
}
__device__ __forceinline__ float2 bf2f2(unsigned int p) {
    float2 r;
    r.x = __uint_as_float(p << 16);
    r.y = __uint_as_float(p & 0xFFFF0000u);
    return r;
}
__device__ __forceinline__ void unpack_edge(unsigned long long p, int& s, float& eav) {
    s = (int)(unsigned int)(p & 0xFFFFFFFFull);
    eav = __uint_as_float((unsigned int)(p >> 32));
}

// 256-thread exclusive scan (ONE internal barrier; all 256 must call)
__device__ __forceinline__ int block_excl_scan_256(int v, int tid, int* wsum) {
    int lane = tid & 63, wv = tid >> 6;
    int x = v;
    #pragma unroll
    for (int off = 1; off < 64; off <<= 1) {
        int y = __shfl_up(x, off);
        if (lane >= off) x += y;
    }
    if (lane == 63) wsum[wv] = x;
    __syncthreads();
    int wpre = 0;
    #pragma unroll
    for (int w = 0; w < 4; w++)
        if (w < wv) wpre += wsum[w];
    return wpre + x - v;
}

// ---------------- hist: 196-bin bucket histogram (LDS) + ea sum ----------------
__global__ __launch_bounds__(256) void hist_kernel(const int* __restrict__ ei,
                                                   const float* __restrict__ ea,
                                                   int* __restrict__ bucketHist,
                                                   float* __restrict__ easum) {
    __shared__ int h[256];
    int tid = threadIdx.x;
    h[tid] = 0;
    __syncthreads();
    float s = 0.f;
    for (int i = blockIdx.x * 256 + tid; i < EE; i += gridDim.x * 256) {
        atomicAdd(&h[ei[EE + i] >> 8], 1);
        s += ea[i];
    }
    __syncthreads();
    if (tid < NBKT && h[tid] > 0) atomicAdd(&bucketHist[tid], h[tid]);
    #pragma unroll
    for (int off = 32; off > 0; off >>= 1) s += __shfl_xor(s, off);
    if ((tid & 63) == 0) atomicAdd(easum, s);
}

// ---------------- bucket scan: bases + cursors + tail sentinels ----------------
__global__ void bucket_scan(const int* __restrict__ bucketHist,
                            int* __restrict__ bucketBase,
                            int* __restrict__ bucketCursor,
                            int* __restrict__ indptr) {
    __shared__ int wsum[4];
    int tid = threadIdx.x;  // 256
    int v = (tid < NBKT) ? bucketHist[tid] : 0;
    int excl = block_excl_scan_256(v, tid, wsum);
    if (tid <= NBKT) bucketBase[tid] = (tid == NBKT) ? EE : excl;
    if (tid < NBKT) bucketCursor[tid] = excl;
    if (tid == 0) indptr[NN] = EE;
}

// ---------------- stage1: LDS bin by bucket, block-reserve, copy-out ----------------
__global__ __launch_bounds__(256) void stage1_kernel(const int* __restrict__ ei,
                                                     const float* __restrict__ ea,
                                                     int* __restrict__ bucketCursor,
                                                     int* __restrict__ Adst,
                                                     int* __restrict__ Asrc,
                                                     float* __restrict__ Aea) {
    __shared__ int cnt[256];
    __shared__ int basel[256];
    __shared__ int gbase[256];
    __shared__ int wsum[4];
    __shared__ int sdst[2048];
    __shared__ int ssrc[2048];
    __shared__ float sea[2048];
    int tid = threadIdx.x;
    int base = blockIdx.x * 2048;
    cnt[tid] = 0;
    __syncthreads();
    int d[8], s[8], r[8], bk[8];
    float e[8];
    #pragma unroll
    for (int k = 0; k < 8; k++) {
        int i = base + k * 256 + tid;
        if (i < EE) {
            d[k] = ei[EE + i];
            s[k] = ei[i];
            e[k] = ea[i];
            bk[k] = d[k] >> 8;
            r[k] = atomicAdd(&cnt[bk[k]], 1);   // LDS returning atomic: cheap
        } else d[k] = -1;
    }
    __syncthreads();
    int v = cnt[tid];
    int excl = block_excl_scan_256(v, tid, wsum);
    basel[tid] = excl;
    if (tid < NBKT) gbase[tid] = atomicAdd(&bucketCursor[tid], v);
    __syncthreads();
    #pragma unroll
    for (int k = 0; k < 8; k++) {
        if (d[k] >= 0) {
            int slot = basel[bk[k]] + r[k];
            sdst[slot] = d[k];
            ssrc[slot] = s[k];
            sea[slot] = e[k];
        }
    }
    __syncthreads();
    int total = basel[255] + cnt[255];
    for (int slot = tid; slot < total; slot += 256) {
        int dd = sdst[slot];
        int b = dd >> 8;
        int pos = gbase[b] + (slot - basel[b]);
        Adst[pos] = dd;
        Asrc[pos] = ssrc[slot];
        Aea[pos] = sea[slot];
    }
}

// ---------------- stage2: per-bucket counting sort -> indptr + edgedat ----------------
__global__ __launch_bounds__(256) void stage2_kernel(const int* __restrict__ bucketBase,
                                                     const int* __restrict__ Adst,
                                                     const int* __restrict__ Asrc,
                                                     const float* __restrict__ Aea,
                                                     int* __restrict__ indptr,
                                                     unsigned long long* __restrict__ edgedat) {
    __shared__ int cnt[256];
    __shared__ int dbase[256];
    __shared__ int wsum[4];
    int tid = threadIdx.x;
    int b = blockIdx.x;
    int start = bucketBase[b], end = bucketBase[b + 1];
    cnt[tid] = 0;
    __syncthreads();
    for (int i = start + tid; i < end; i += 256) atomicAdd(&cnt[Adst[i] & 255], 1);
    __syncthreads();
    int v = cnt[tid];
    int excl = block_excl_scan_256(v, tid, wsum);
    dbase[tid] = excl;
    __syncthreads();
    int n = b * 256 + tid;
    if (n < NN) indptr[n] = start + excl;
    cnt[tid] = 0;          // reuse as per-dst cursor
    __syncthreads();
    for (int i = start + tid; i < end; i += 256) {
        int dl = Adst[i] & 255;
        int r = atomicAdd(&cnt[dl], 1);
        int pos = start + dbase[dl] + r;
        edgedat[pos] = (unsigned long long)(unsigned int)Asrc[i] |
                       ((unsigned long long)__float_as_uint(Aea[i]) << 32);
    }
}

// ---------------- per-head attention constants + ea mean ----------------
__global__ void prep_kernel(const float* __restrict__ We1, const float* __restrict__ ae1,
                            const float* __restrict__ We2, const float* __restrict__ ae2,
                            float* __restrict__ consts) {
    int lane = threadIdx.x;
    if (lane < 4) {
        float s = 0.f;
        for (int c = 0; c < 32; c++) s += We1[lane * 32 + c] * ae1[lane * 32 + c];
        consts[2 + lane] = s;
    } else if (lane == 4) {
        float s = 0.f;
        for (int c = 0; c < 32; c++) s += We2[c] * ae2[c];
        consts[6] = s;
    } else if (lane == 5) {
        consts[1] = consts[0] / (float)EE;
    }
}

// ---------------- prep W1 into MFMA B-fragment order, split hi/lo bf16 ----------------
__global__ __launch_bounds__(256) void prep_w1_kernel(const float* __restrict__ W1,
                                                      unsigned short* __restrict__ Whi,
                                                      unsigned short* __restrict__ Wlo) {
    int t = blockIdx.x * 256 + threadIdx.x;   // 4096 threads: (nt,kt,lane)
    int lane = t & 63;
    int kt = (t >> 6) & 7;
    int nt = t >> 9;
    int kbase = kt * 32 + (lane >> 4) * 8;
    int col = nt * 16 + (lane & 15);
    size_t obase = (size_t)t * 8;
    #pragma unroll
    for (int j = 0; j < 8; j++) {
        float w = W1[(size_t)(kbase + j) * HC + col];
        unsigned short h = f2bf(w);
        float hf = bf2f(h);
        Whi[obase + j] = h;
        Wlo[obase + j] = f2bf(w - hf);
    }
}

// ---------------- gemm1 via MFMA split-bf16: xs1 = x @ W1 ----------------
__global__ __launch_bounds__(64) void gemm1_mfma(const float* __restrict__ x,
                                                 const unsigned short* __restrict__ Whi,
                                                 const unsigned short* __restrict__ Wlo,
                                                 unsigned short* __restrict__ xs1b) {
    int lane = threadIdx.x;           // 64
    int row0 = blockIdx.x * 16;       // NN = 16 * 3125 exactly
    int m = lane & 15;
    int q = lane >> 4;
    f32x4 acc[8];
    #pragma unroll
    for (int nt = 0; nt < 8; nt++) acc[nt] = {0.f, 0.f, 0.f, 0.f};
    const float* xrow = x + (size_t)(row0 + m) * IN_DIM + q * 8;
    #pragma unroll
    for (int kt = 0; kt < 8; kt++) {
        float4 v0 = *(const float4*)(xrow + kt * 32);
        float4 v1 = *(const float4*)(xrow + kt * 32 + 4);
        float vv[8] = {v0.x, v0.y, v0.z, v0.w, v1.x, v1.y, v1.z, v1.w};
        short8 ahi, alo;
        #pragma unroll
        for (int j = 0; j < 8; j++) {
            unsigned short h = f2bf(vv[j]);
            ahi[j] = (short)h;
            alo[j] = (short)f2bf(vv[j] - bf2f(h));
        }
        #pragma unroll
        for (int nt = 0; nt < 8; nt++) {
            size_t fb = ((size_t)(nt * 8 + kt) * 64 + lane) * 8;
            short8 bhi = *(const short8*)(Whi + fb);
            short8 blo = *(const short8*)(Wlo + fb);
            acc[nt] = __builtin_amdgcn_mfma_f32_16x16x32_bf16(ahi, bhi, acc[nt], 0, 0, 0);
            acc[nt] = __builtin_amdgcn_mfma_f32_16x16x32_bf16(ahi, blo, acc[nt], 0, 0, 0);
            acc[nt] = __builtin_amdgcn_mfma_f32_16x16x32_bf16(alo, bhi, acc[nt], 0, 0, 0);
        }
    }
    // C/D layout: col = lane&15, row = (lane>>4)*4 + reg
    #pragma unroll
    for (int nt = 0; nt < 8; nt++) {
        #pragma unroll
        for (int reg = 0; reg < 4; reg++) {
            int row = row0 + q * 4 + reg;
            xs1b[(size_t)row * HC + nt * 16 + m] = f2bf(acc[nt][reg]);
        }
    }
}

// ---------------- fp32 tiled GEMM (gemm2) ----------------
template <int TM, int TN, int TK, int RM, int RN, bool BF16OUT>
__global__ __launch_bounds__(256) void gemm_kernel(const float* __restrict__ A,
                                                   const float* __restrict__ B,
                                                   void* __restrict__ Cv, int M, int K) {
    static_assert(TM * TN == 256 * RM * RN, "thread coverage");
    static_assert(RN % 2 == 0, "pairable");
    __shared__ float As[TK][TM + 4];
    __shared__ float Bs[TK][TN];
    int tid = threadIdx.x;
    int tx = tid % (TN / RN);
    int ty = tid / (TN / RN);
    int blockRow = blockIdx.x * TM;
    float acc[RM][RN];
    #pragma unroll
    for (int i = 0; i < RM; i++)
        #pragma unroll
        for (int j = 0; j < RN; j++) acc[i][j] = 0.f;

    for (int k0 = 0; k0 < K; k0 += TK) {
        #pragma unroll
        for (int l = 0; l < TM * TK; l += 256 * 4) {
            int ll = l + tid * 4;
            if (ll < TM * TK) {
                int r = ll / TK, kk = ll % TK;
                float4 v = make_float4(0.f, 0.f, 0.f, 0.f);
                int gr = blockRow + r;
                if (gr < M) v = *(const float4*)(A + (size_t)gr * K + k0 + kk);
                As[kk + 0][r] = v.x;
                As[kk + 1][r] = v.y;
                As[kk + 2][r] = v.z;
                As[kk + 3][r] = v.w;
            }
        }
        #pragma unroll
        for (int l = 0; l < TK * TN; l += 256 * 4) {
            int ll = l + tid * 4;
            if (ll < TK * TN) {
                int kk = ll / TN, c = ll % TN;
                *(float4*)&Bs[kk][c] = *(const float4*)(B + (size_t)(k0 + kk) * TN + c);
            }
        }
        __syncthreads();
        #pragma unroll
        for (int k = 0; k < TK; k++) {
            float af[RM], bf[RN];
            #pragma unroll
            for (int i = 0; i < RM; i++) af[i] = As[k][ty * RM + i];
            #pragma unroll
            for (int j = 0; j < RN; j++) bf[j] = Bs[k][tx * RN + j];
            #pragma unroll
            for (int i = 0; i < RM; i++)
                #pragma unroll
                for (int j = 0; j < RN; j++) acc[i][j] += af[i] * bf[j];
        }
        __syncthreads();
    }
    #pragma unroll
    for (int i = 0; i < RM; i++) {
        int gr = blockRow + ty * RM + i;
        if (gr < M) {
            if (BF16OUT) {
                unsigned short* C = (unsigned short*)Cv;
                #pragma unroll
                for (int j = 0; j < RN; j += 2) {
                    unsigned int pk = (unsigned int)f2bf(acc[i][j]) |
                                      ((unsigned int)f2bf(acc[i][j + 1]) << 16);
                    *(unsigned int*)(C + (size_t)gr * TN + tx * RN + j) = pk;
                }
            } else {
                float* C = (float*)Cv;
                #pragma unroll
                for (int j = 0; j < RN; j++) C[(size_t)gr * TN + tx * RN + j] = acc[i][j];
            }
        }
    }
}

// ---------------- attention logits per node (bf16 inputs) ----------------
__global__ void al1_kernel(const unsigned short* __restrict__ xs1b, const float* __restrict__ as1,
                           const float* __restrict__ ad1, float* __restrict__ als,
                           float* __restrict__ ald) {
    int t = blockIdx.x * 256 + threadIdx.x;
    if (t >= NN * 4) return;
    int h = t & 3;
    const unsigned int* xp = (const unsigned int*)(xs1b + (size_t)t * 32);
    const float* ap = as1 + h * 32;
    const float* dp = ad1 + h * 32;
    float s = 0.f, d = 0.f;
    #pragma unroll
    for (int q = 0; q < 16; q++) {
        float2 v = bf2f2(xp[q]);
        s += v.x * ap[q * 2] + v.y * ap[q * 2 + 1];
        d += v.x * dp[q * 2] + v.y * dp[q * 2 + 1];
    }
    als[t] = s;
    ald[t] = d;
}

__global__ void al2_kernel(const unsigned short* __restrict__ xs2b, const float* __restrict__ as2,
                           const float* __restrict__ ad2, float* __restrict__ als,
                           float* __restrict__ ald) {
    int t = blockIdx.x * 256 + threadIdx.x;
    if (t >= NN) return;
    const unsigned int* xp = (const unsigned int*)(xs2b + (size_t)t * 32);
    float s = 0.f, d = 0.f;
    #pragma unroll
    for (int q = 0; q < 16; q++) {
        float2 v = bf2f2(xp[q]);
        s += v.x * as2[q * 2] + v.y * as2[q * 2 + 1];
        d += v.x * ad2[q * 2] + v.y * ad2[q * 2 + 1];
    }
    als[t] = s;
    ald[t] = d;
}

// ---------------- conv1 aggregation: one wave per dst node (no-max softmax) ----------------
__global__ __launch_bounds__(256) void gat1_agg(
    const unsigned short* __restrict__ xs1b, const float* __restrict__ als,
    const float* __restrict__ ald, const unsigned long long* __restrict__ edgedat,
    const int* __restrict__ indptr, const float* __restrict__ consts,
    const float* __restrict__ b1, const float* __restrict__ g1,
    const float* __restrict__ be1, float* __restrict__ h1out) {
    __shared__ float exbuf[4][CAP1 * 4];
    __shared__ int srcbuf[4][CAP1];
    int wv = threadIdx.x >> 6;
    int lane = threadIdx.x & 63;
    int n = blockIdx.x * 4 + wv;
    int start = indptr[n];
    int deg = indptr[n + 1] - start;
    float ea_mean = consts[1];
    float ce[4] = {consts[2], consts[3], consts[4], consts[5]};
    float4 a4d = *(const float4*)(ald + (size_t)n * 4);
    float aldh[4] = {a4d.x, a4d.y, a4d.z, a4d.w};
    float4 a4s = *(const float4*)(als + (size_t)n * 4);
    float alsn[4] = {a4s.x, a4s.y, a4s.z, a4s.w};
    float ex0[4], sm[4];
    #pragma unroll
    for (int h = 0; h < 4; h++) {
        ex0[h] = __expf(lrelu(alsn[h] + aldh[h] + ea_mean * ce[h]));
        sm[h] = 0.f;
    }
    const unsigned long long* edp = edgedat + start;
    // single pass: alpha -> exp -> LDS + running sum (logits bounded; no max needed)
    for (int i = lane; i < deg; i += 64) {
        int s; float eav;
        unpack_edge(edp[i], s, eav);
        float4 v4 = *(const float4*)(als + (size_t)s * 4);
        float alv[4] = {v4.x, v4.y, v4.z, v4.w};
        bool st = (i < CAP1);
        if (st) srcbuf[wv][i] = s * HC;   // element offset: kills per-lane mul in gather
        #pragma unroll
        for (int h = 0; h < 4; h++) {
            float exv = __expf(lrelu(alv[h] + aldh[h] + eav * ce[h]));
            if (st) exbuf[wv][i * 4 + h] = exv;
            sm[h] += exv;
        }
    }
    #pragma unroll
    for (int h = 0; h < 4; h++)
        for (int off = 32; off > 0; off >>= 1) sm[h] += __shfl_xor(sm[h], off);
    float inv[4];
    #pragma unroll
    for (int h = 0; h < 4; h++) inv[h] = 1.0f / (sm[h] + ex0[h] + 1e-16f);
    // pre-normalize LDS weights (once, instead of per-lane in the gather)
    int mcap = deg < CAP1 ? deg : CAP1;
    for (int i = lane; i < mcap; i += 64) {
        #pragma unroll
        for (int h = 0; h < 4; h++) exbuf[wv][i * 4 + h] *= inv[h];
    }
    // gather phase: lane holds features c, c+1
    int c = lane * 2;
    int h = lane >> 4;
    float wsl = ex0[h] * inv[h];
    float2 vself = bf2f2(*(const unsigned int*)(xs1b + (size_t)n * HC + c));
    float accx = vself.x * wsl, accy = vself.y * wsl;
    int i = 0;
    for (; i + 4 <= mcap; i += 4) {
        float w0 = exbuf[wv][(i + 0) * 4 + h];
        float w1 = exbuf[wv][(i + 1) * 4 + h];
        float w2 = exbuf[wv][(i + 2) * 4 + h];
        float w3 = exbuf[wv][(i + 3) * 4 + h];
        int o0 = srcbuf[wv][i + 0], o1 = srcbuf[wv][i + 1];
        int o2 = srcbuf[wv][i + 2], o3 = srcbuf[wv][i + 3];
        float2 v0 = bf2f2(*(const unsigned int*)(xs1b + o0 + c));
        float2 v1 = bf2f2(*(const unsigned int*)(xs1b + o1 + c));
        float2 v2 = bf2f2(*(const unsigned int*)(xs1b + o2 + c));
        float2 v3 = bf2f2(*(const unsigned int*)(xs1b + o3 + c));
        accx += v0.x * w0; accy += v0.y * w0;
        accx += v1.x * w1; accy += v1.y * w1;
        accx += v2.x * w2; accy += v2.y * w2;
        accx += v3.x * w3; accy += v3.y * w3;
    }
    for (; i < mcap; i++) {
        float w0 = exbuf[wv][i * 4 + h];
        int o0 = srcbuf[wv][i];
        float2 v0 = bf2f2(*(const unsigned int*)(xs1b + o0 + c));
        accx += v0.x * w0; accy += v0.y * w0;
    }
    for (; i < deg; i++) {  // spill fallback (deg > CAP1): recompute
        int s; float eav;
        unpack_edge(edp[i], s, eav);
        float a = lrelu(als[(size_t)s * 4 + h] + aldh[h] + eav * ce[h]);
        float w0 = __expf(a) * inv[h];
        float2 v0 = bf2f2(*(const unsigned int*)(xs1b + (size_t)s * HC + c));
        accx += v0.x * w0; accy += v0.y * w0;
    }
    float o0 = accx + b1[c];
    float o1 = accy + b1[c + 1];
    o0 = o0 * (g1[c] * BN_RS) + be1[c];
    o1 = o1 * (g1[c + 1] * BN_RS) + be1[c + 1];
    o0 = elu(o0);
    o1 = elu(o1);
    *(float2*)(h1out + (size_t)n * HC + c) = make_float2(o0, o1);
}

// ---------------- conv2 aggregation + fused MLP heads (no-max softmax) ----------------
__global__ __launch_bounds__(256) void gat2_agg(
    const unsigned short* __restrict__ xs2b, const float* __restrict__ als,
    const float* __restrict__ ald, const unsigned long long* __restrict__ edgedat,
    const int* __restrict__ indptr, const float* __restrict__ consts,
    const float* __restrict__ b2, const float* __restrict__ g2, const float* __restrict__ be2,
    const float* __restrict__ Wc1, const float* __restrict__ bc1,
    const float* __restrict__ Wc2, const float* __restrict__ bc2,
    const float* __restrict__ Wr1, const float* __restrict__ br1,
    const float* __restrict__ Wr2, const float* __restrict__ br2,
    float* __restrict__ hout, float* __restrict__ cls, float* __restrict__ reg) {
    __shared__ float exbuf[4][CAP2];
    __shared__ int srcbuf[4][CAP2];
    __shared__ float hbuf[4][32];
    int wv = threadIdx.x >> 6;
    int lane = threadIdx.x & 63;
    int n = blockIdx.x * 4 + wv;
    int start = indptr[n];
    int deg = indptr[n + 1] - start;
    float ea_mean = consts[1];
    float ce = consts[6];
    float aldn = ald[n];
    float ex0 = __expf(lrelu(als[n] + aldn + ea_mean * ce));
    float sm = 0.f;
    const unsigned long long* edp = edgedat + start;
    for (int i = lane; i < deg; i += 64) {
        int s; float eav;
        unpack_edge(edp[i], s, eav);
        float exv = __expf(lrelu(als[s] + aldn + eav * ce));
        if (i < CAP2) { srcbuf[wv][i] = s * CD; exbuf[wv][i] = exv; }
        sm += exv;
    }
    for (int off = 32; off > 0; off >>= 1) sm += __shfl_xor(sm, off);
    float invd = 1.0f / (sm + ex0 + 1e-16f);
    int mcap = deg < CAP2 ? deg : CAP2;
    for (int i = lane; i < mcap; i += 64) exbuf[wv][i] *= invd;
    int quarter = lane >> 4;
    int cl = lane & 15;
    int c = cl * 2;
    float accx = 0.f, accy = 0.f;
    if (quarter == 0) {
        float2 vs = bf2f2(*(const unsigned int*)(xs2b + (size_t)n * CD + c));
        float wsl = ex0 * invd;
        accx = vs.x * wsl; accy = vs.y * wsl;
    }
    for (int i = quarter; i < mcap; i += 4) {
        float w0 = exbuf[wv][i];
        int o0 = srcbuf[wv][i];
        float2 v0 = bf2f2(*(const unsigned int*)(xs2b + o0 + c));
        accx += v0.x * w0; accy += v0.y * w0;
    }
    for (int i = CAP2 + quarter; i < deg; i += 4) {  // spill fallback
        int s; float eav;
        unpack_edge(edp[i], s, eav);
        float w0 = __expf(lrelu(als[s] + aldn + eav * ce)) * invd;
        float2 v0 = bf2f2(*(const unsigned int*)(xs2b + (size_t)s * CD + c));
        accx += v0.x * w0; accy += v0.y * w0;
    }
    accx += __shfl_xor(accx, 16); accy += __shfl_xor(accy, 16);
    accx += __shfl_xor(accx, 32); accy += __shfl_xor(accy, 32);
    if (lane < 16) {
        float o0 = accx + b2[c];
        float o1 = accy + b2[c + 1];
        o0 = o0 * (g2[c] * BN_RS) + be2[c];
        o1 = o1 * (g2[c + 1] * BN_RS) + be2[c + 1];
        o0 = elu(o0);
        o1 = elu(o1);
        hbuf[wv][c] = o0;
        hbuf[wv][c + 1] = o1;
        *(float2*)(hout + (size_t)n * CD + c) = make_float2(o0, o1);
    }
    __syncthreads();
    float r0 = 0.f, r1 = 0.f;
    if (lane < 32) {
        int j = lane & 15;
        bool iscls = lane < 16;
        float s = iscls ? bc1[j] : br1[j];
        #pragma unroll
        for (int cc = 0; cc < 32; cc++) {
            float w = iscls ? Wc1[cc * 16 + j] : Wr1[cc * 16 + j];
            s += hbuf[wv][cc] * w;
        }
        s = fmaxf(s, 0.f);
        if (iscls) { r0 = s * Wc2[j * 2]; r1 = s * Wc2[j * 2 + 1]; }
        else       { r0 = s * Wr2[j]; }
    }
    #pragma unroll
    for (int off = 1; off < 16; off <<= 1) {
        r0 += __shfl_xor(r0, off);
        r1 += __shfl_xor(r1, off);
    }
    if (lane == 0)  *(float2*)(cls + (size_t)n * 2) = make_float2(r0 + bc2[0], r1 + bc2[1]);
    if (lane == 16) reg[n] = r0 + br2[0];
}

// ---------------- launch ----------------
extern "C" void kernel_launch(void* const* d_in, const int* in_sizes, int n_in,
                              void* d_out, int out_size, void* d_ws, size_t ws_size,
                              hipStream_t stream) {
    const float* x   = (const float*)d_in[0];
    const int*   ei  = (const int*)d_in[1];
    const float* ea  = (const float*)d_in[2];
    const float* W1  = (const float*)d_in[3];
    const float* as1 = (const float*)d_in[4];
    const float* ad1 = (const float*)d_in[5];
    const float* We1 = (const float*)d_in[6];
    const float* ae1 = (const float*)d_in[7];
    const float* b1  = (const float*)d_in[8];
    const float* g1  = (const float*)d_in[9];
    const float* be1 = (const float*)d_in[10];
    const float* W2  = (const float*)d_in[11];
    const float* as2 = (const float*)d_in[12];
    const float* ad2 = (const float*)d_in[13];
    const float* We2 = (const float*)d_in[14];
    const float* ae2 = (const float*)d_in[15];
    const float* b2  = (const float*)d_in[16];
    const float* g2  = (const float*)d_in[17];
    const float* be2 = (const float*)d_in[18];
    const float* Wc1 = (const float*)d_in[19];
    const float* bc1 = (const float*)d_in[20];
    const float* Wc2 = (const float*)d_in[21];
    const float* bc2 = (const float*)d_in[22];
    const float* Wr1 = (const float*)d_in[23];
    const float* br1 = (const float*)d_in[24];
    const float* Wr2 = (const float*)d_in[25];
    const float* br2 = (const float*)d_in[26];

    char* ws = (char*)d_ws;
    unsigned short* xs1b = (unsigned short*)(ws + 0);          // N*128 bf16 = 12.8 MB
    float* h1            = (float*)(ws + 12800000);            // N*128 f32 = 25.6 MB
    // staging arrays alias h1 (consumed by stage2 before gat1 writes h1)
    int*   Adst          = (int*)(ws + 12800000);              // E = 6.4 MB
    int*   Asrc          = (int*)(ws + 19200000);              // E = 6.4 MB
    float* Aea           = (float*)(ws + 25600000);            // E = 6.4 MB (ends 32.0 MB)
    unsigned short* xs2b = (unsigned short*)(ws + 38400000);   // N*32 bf16 = 3.2 MB
    float* als1          = (float*)(ws + 41600000);            // N*4
    float* ald1          = (float*)(ws + 42400000);            // N*4
    float* als2          = (float*)(ws + 43200000);            // N
    float* ald2          = (float*)(ws + 43400000);            // N
    float* consts        = (float*)(ws + 43600000);            // 8 floats
    int*   bucketHist    = (int*)(ws + 43600128);              // 196
    int*   bucketBase    = (int*)(ws + 43601024);              // 197
    int*   bucketCursor  = (int*)(ws + 43601920);              // 196
    int*   indptr        = (int*)(ws + 43602816);              // N+1
    unsigned long long* edgedat = (unsigned long long*)(ws + 43802824);  // E*8 = 12.8 MB -> ends 56602824
    unsigned short* W1hi = (unsigned short*)(ws + 56602832);   // 32768 bf16 = 64 KB
    unsigned short* W1lo = (unsigned short*)(ws + 56668368);   // 64 KB (ends ~56.73 MB)

    float* out_cls = (float*)d_out;            // [N,2]
    float* out_reg = out_cls + 2 * NN;         // [N]
    float* out_h   = out_cls + 3 * NN;         // [N,32]

    hipMemsetAsync(bucketHist, 0, NBKT * sizeof(int), stream);
    hipMemsetAsync(consts, 0, 8 * sizeof(float), stream);

    // CSR build (no global returning atomics) + W1 prepack
    hist_kernel<<<256, 256, 0, stream>>>(ei, ea, bucketHist, consts);
    prep_w1_kernel<<<16, 256, 0, stream>>>(W1, W1hi, W1lo);
    bucket_scan<<<1, 256, 0, stream>>>(bucketHist, bucketBase, bucketCursor, indptr);
    stage1_kernel<<<S1_B, 256, 0, stream>>>(ei, ea, bucketCursor, Adst, Asrc, Aea);
    stage2_kernel<<<NBKT, 256, 0, stream>>>(bucketBase, Adst, Asrc, Aea, indptr, edgedat);
    prep_kernel<<<1, 64, 0, stream>>>(We1, ae1, We2, ae2, consts);

    // conv1: MFMA split-bf16 GEMM
    gemm1_mfma<<<NN / 16, 64, 0, stream>>>(x, W1hi, W1lo, xs1b);
    al1_kernel<<<(NN * 4 + 255) / 256, 256, 0, stream>>>(xs1b, as1, ad1, als1, ald1);
    gat1_agg<<<NN / 4, 256, 0, stream>>>(xs1b, als1, ald1, edgedat, indptr, consts,
                                         b1, g1, be1, h1);
    // conv2
    gemm_kernel<128, 32, 32, 8, 2, true><<<(NN + 127) / 128, 256, 0, stream>>>(h1, W2, xs2b, NN, HC);
    al2_kernel<<<(NN + 255) / 256, 256, 0, stream>>>(xs2b, as2, ad2, als2, ald2);
    gat2_agg<<<NN / 4, 256, 0, stream>>>(xs2b, als2, ald2, edgedat, indptr, consts,
                                         b2, g2, be2, Wc1, bc1, Wc2, bc2,
                                         Wr1, br1, Wr2, br2, out_h, out_cls, out_reg);
}

// Round 10
// 361.447 us; speedup vs baseline: 1.4058x; 1.1192x over previous
//
#include <hip/hip_runtime.h>
#include <cstdint>
#include <cstddef>

// ---------------- problem constants ----------------
#define NN 50000
#define EE 1600000
#define IN_DIM 256
#define HC 128      // HEADS*C
#define CD 32       // C
#define BN_RS 0.9999950000374997f  // 1/sqrt(1+1e-5)

#define CAP1 128
#define CAP2 128
#define NBKT 196        // ceil(NN/256) buckets of 256 dst nodes
#define S1_B 782        // (EE+2047)/2048
#define HIST_B 160
#define G1_B 782        // ceil(NN/64) gemm blocks (4 waves x 16 rows)

typedef __attribute__((ext_vector_type(8))) short short8;   // 8 bf16 (bit pattern)
typedef __attribute__((ext_vector_type(4))) float f32x4;

// ---------------- small helpers ----------------
__device__ __forceinline__ float lrelu(float a) { return a > 0.f ? a : 0.2f * a; }
__device__ __forceinline__ float elu(float a) { return a > 0.f ? a : (__expf(a) - 1.f); }

__device__ __forceinline__ unsigned short f2bf(float f) {
    unsigned int u = __float_as_uint(f);
    unsigned int r = (u + 0x7FFFu + ((u >> 16) & 1u)) >> 16;
    return (unsigned short)r;
}
__device__ __forceinline__ float bf2f(unsigned short b) {
    return __uint_as_float(((unsigned int)b) << 16);
}
__device__ __forceinline__ float2 bf2f2(unsigned int p) {
    float2 r;
    r.x = __uint_as_float(p << 16);
    r.y = __uint_as_float(p & 0xFFFF0000u);
    return r;
}
__device__ __forceinline__ void unpack_edge(unsigned long long p, int& s, float& eav) {
    s = (int)(unsigned int)(p & 0xFFFFFFFFull);
    eav = __uint_as_float((unsigned int)(p >> 32));
}

// 256-thread exclusive scan (ONE internal barrier; all 256 must call)
__device__ __forceinline__ int block_excl_scan_256(int v, int tid, int* wsum) {
    int lane = tid & 63, wv = tid >> 6;
    int x = v;
    #pragma unroll
    for (int off = 1; off < 64; off <<= 1) {
        int y = __shfl_up(x, off);
        if (lane >= off) x += y;
    }
    if (lane == 63) wsum[wv] = x;
    __syncthreads();
    int wpre = 0;
    #pragma unroll
    for (int w = 0; w < 4; w++)
        if (w < wv) wpre += wsum[w];
    return wpre + x - v;
}

// ---------------- K0: prep W1 frags + W2 frags + attention consts ----------------
__global__ __launch_bounds__(256) void k0_prep(const float* __restrict__ W1,
                                               const float* __restrict__ W2,
                                               const float* __restrict__ We1,
                                               const float* __restrict__ ae1,
                                               const float* __restrict__ We2,
                                               const float* __restrict__ ae2,
                                               unsigned short* __restrict__ W1hi,
                                               unsigned short* __restrict__ W1lo,
                                               unsigned short* __restrict__ W2hi,
                                               unsigned short* __restrict__ W2lo,
                                               float* __restrict__ consts) {
    int blk = blockIdx.x;
    int tid = threadIdx.x;
    if (blk < 16) {
        // W1 [256,128] -> frag order ((nt*8+kt)*64+lane)*8+j, split hi/lo
        int t = blk * 256 + tid;
        int lane = t & 63;
        int kt = (t >> 6) & 7;
        int nt = t >> 9;
        int kbase = kt * 32 + (lane >> 4) * 8;
        int col = nt * 16 + (lane & 15);
        size_t obase = (size_t)t * 8;
        #pragma unroll
        for (int j = 0; j < 8; j++) {
            float w = W1[(size_t)(kbase + j) * HC + col];
            unsigned short h = f2bf(w);
            W1hi[obase + j] = h;
            W1lo[obase + j] = f2bf(w - bf2f(h));
        }
    } else if (blk < 18) {
        // W2 [128,32] -> frag order ((nt*4+kt)*64+lane)*8+j, split hi/lo
        int t = (blk - 16) * 256 + tid;  // 0..511
        int lane = t & 63;
        int kt = (t >> 6) & 3;
        int nt = t >> 8;
        int kbase = kt * 32 + (lane >> 4) * 8;
        int col = nt * 16 + (lane & 15);
        size_t obase = (size_t)t * 8;
        #pragma unroll
        for (int j = 0; j < 8; j++) {
            float w = W2[(size_t)(kbase + j) * CD + col];
            unsigned short h = f2bf(w);
            W2hi[obase + j] = h;
            W2lo[obase + j] = f2bf(w - bf2f(h));
        }
    } else {
        // attention edge constants
        if (tid < 4) {
            float s = 0.f;
            for (int c = 0; c < 32; c++) s += We1[tid * 32 + c] * ae1[tid * 32 + c];
            consts[2 + tid] = s;
        } else if (tid == 4) {
            float s = 0.f;
            for (int c = 0; c < 32; c++) s += We2[c] * ae2[c];
            consts[6] = s;
        }
    }
}

// ---------------- K_A: hist (LDS) + gemm1 (MFMA split-bf16), fused ----------------
__global__ __launch_bounds__(256) void kA_hist_gemm1(const int* __restrict__ ei,
                                                     const float* __restrict__ ea,
                                                     const float* __restrict__ x,
                                                     const unsigned short* __restrict__ Whi,
                                                     const unsigned short* __restrict__ Wlo,
                                                     int* __restrict__ bucketHist,
                                                     float* __restrict__ easum,
                                                     unsigned short* __restrict__ xs1b) {
    __shared__ int h[256];
    int tid = threadIdx.x;
    if (blockIdx.x < HIST_B) {
        // ---- hist path ----
        h[tid] = 0;
        __syncthreads();
        float s = 0.f;
        for (int i = blockIdx.x * 256 + tid; i < EE; i += HIST_B * 256) {
            atomicAdd(&h[ei[EE + i] >> 8], 1);
            s += ea[i];
        }
        __syncthreads();
        if (tid < NBKT && h[tid] > 0) atomicAdd(&bucketHist[tid], h[tid]);
        #pragma unroll
        for (int off = 32; off > 0; off >>= 1) s += __shfl_xor(s, off);
        if ((tid & 63) == 0) atomicAdd(easum, s);
    } else {
        // ---- gemm1 path: wave per 16 rows, 4 waves/block ----
        int lane = tid & 63, wv = tid >> 6;
        int row0 = (blockIdx.x - HIST_B) * 64 + wv * 16;
        if (row0 >= NN) return;
        int m = lane & 15;
        int q = lane >> 4;
        f32x4 acc[8];
        #pragma unroll
        for (int nt = 0; nt < 8; nt++) acc[nt] = {0.f, 0.f, 0.f, 0.f};
        const float* xrow = x + (size_t)(row0 + m) * IN_DIM + q * 8;
        #pragma unroll
        for (int kt = 0; kt < 8; kt++) {
            float4 v0 = *(const float4*)(xrow + kt * 32);
            float4 v1 = *(const float4*)(xrow + kt * 32 + 4);
            float vv[8] = {v0.x, v0.y, v0.z, v0.w, v1.x, v1.y, v1.z, v1.w};
            short8 ahi, alo;
            #pragma unroll
            for (int j = 0; j < 8; j++) {
                unsigned short hh = f2bf(vv[j]);
                ahi[j] = (short)hh;
                alo[j] = (short)f2bf(vv[j] - bf2f(hh));
            }
            #pragma unroll
            for (int nt = 0; nt < 8; nt++) {
                size_t fb = ((size_t)(nt * 8 + kt) * 64 + lane) * 8;
                short8 bhi = *(const short8*)(Whi + fb);
                short8 blo = *(const short8*)(Wlo + fb);
                acc[nt] = __builtin_amdgcn_mfma_f32_16x16x32_bf16(ahi, bhi, acc[nt], 0, 0, 0);
                acc[nt] = __builtin_amdgcn_mfma_f32_16x16x32_bf16(ahi, blo, acc[nt], 0, 0, 0);
                acc[nt] = __builtin_amdgcn_mfma_f32_16x16x32_bf16(alo, bhi, acc[nt], 0, 0, 0);
            }
        }
        #pragma unroll
        for (int nt = 0; nt < 8; nt++) {
            #pragma unroll
            for (int reg = 0; reg < 4; reg++) {
                int row = row0 + q * 4 + reg;
                xs1b[(size_t)row * HC + nt * 16 + m] = f2bf(acc[nt][reg]);
            }
        }
    }
}

// ---------------- bucket scan: bases + cursors + sentinels + ea_mean ----------------
__global__ void bucket_scan(const int* __restrict__ bucketHist,
                            int* __restrict__ bucketBase,
                            int* __restrict__ bucketCursor,
                            int* __restrict__ indptr,
                            float* __restrict__ consts) {
    __shared__ int wsum[4];
    int tid = threadIdx.x;  // 256
    int v = (tid < NBKT) ? bucketHist[tid] : 0;
    int excl = block_excl_scan_256(v, tid, wsum);
    if (tid <= NBKT) bucketBase[tid] = (tid == NBKT) ? EE : excl;
    if (tid < NBKT) bucketCursor[tid] = excl;
    if (tid == 0) { indptr[NN] = EE; consts[1] = consts[0] / (float)EE; }
}

// ---------------- K_B: stage1 (bucket bin) + al1, fused ----------------
__global__ __launch_bounds__(256) void kB_stage1_al1(const int* __restrict__ ei,
                                                     const float* __restrict__ ea,
                                                     int* __restrict__ bucketCursor,
                                                     int* __restrict__ Adst,
                                                     int* __restrict__ Asrc,
                                                     float* __restrict__ Aea,
                                                     const unsigned short* __restrict__ xs1b,
                                                     const float* __restrict__ as1,
                                                     const float* __restrict__ ad1,
                                                     float* __restrict__ als,
                                                     float* __restrict__ ald) {
    __shared__ int cnt[256];
    __shared__ int basel[256];
    __shared__ int gbase[256];
    __shared__ int wsum[4];
    __shared__ int sdst[2048];
    __shared__ int ssrc[2048];
    __shared__ float sea[2048];
    int tid = threadIdx.x;
    if (blockIdx.x < S1_B) {
        int base = blockIdx.x * 2048;
        cnt[tid] = 0;
        __syncthreads();
        int d[8], s[8], r[8], bk[8];
        float e[8];
        #pragma unroll
        for (int k = 0; k < 8; k++) {
            int i = base + k * 256 + tid;
            if (i < EE) {
                d[k] = ei[EE + i];
                s[k] = ei[i];
                e[k] = ea[i];
                bk[k] = d[k] >> 8;
                r[k] = atomicAdd(&cnt[bk[k]], 1);   // LDS returning atomic: cheap
            } else d[k] = -1;
        }
        __syncthreads();
        int v = cnt[tid];
        int excl = block_excl_scan_256(v, tid, wsum);
        basel[tid] = excl;
        if (tid < NBKT) gbase[tid] = atomicAdd(&bucketCursor[tid], v);
        __syncthreads();
        #pragma unroll
        for (int k = 0; k < 8; k++) {
            if (d[k] >= 0) {
                int slot = basel[bk[k]] + r[k];
                sdst[slot] = d[k];
                ssrc[slot] = s[k];
                sea[slot] = e[k];
            }
        }
        __syncthreads();
        int total = basel[255] + cnt[255];
        for (int slot = tid; slot < total; slot += 256) {
            int dd = sdst[slot];
            int b = dd >> 8;
            int pos = gbase[b] + (slot - basel[b]);
            Adst[pos] = dd;
            Asrc[pos] = ssrc[slot];
            Aea[pos] = sea[slot];
        }
    } else {
        // ---- al1 path: one thread per (node,head) ----
        int t = (blockIdx.x - S1_B) * 256 + tid;
        if (t < NN * 4) {
            int hh = t & 3;
            const unsigned int* xp = (const unsigned int*)(xs1b + (size_t)t * 32);
            const float* ap = as1 + hh * 32;
            const float* dp = ad1 + hh * 32;
            float s = 0.f, d = 0.f;
            #pragma unroll
            for (int q = 0; q < 16; q++) {
                float2 v = bf2f2(xp[q]);
                s += v.x * ap[q * 2] + v.y * ap[q * 2 + 1];
                d += v.x * dp[q * 2] + v.y * dp[q * 2 + 1];
            }
            als[t] = s;
            ald[t] = d;
        }
    }
}

// ---------------- stage2: per-bucket counting sort -> indptr + edgedat ----------------
__global__ __launch_bounds__(256) void stage2_kernel(const int* __restrict__ bucketBase,
                                                     const int* __restrict__ Adst,
                                                     const int* __restrict__ Asrc,
                                                     const float* __restrict__ Aea,
                                                     int* __restrict__ indptr,
                                                     unsigned long long* __restrict__ edgedat) {
    __shared__ int cnt[256];
    __shared__ int dbase[256];
    __shared__ int wsum[4];
    int tid = threadIdx.x;
    int b = blockIdx.x;
    int start = bucketBase[b], end = bucketBase[b + 1];
    cnt[tid] = 0;
    __syncthreads();
    for (int i = start + tid; i < end; i += 256) atomicAdd(&cnt[Adst[i] & 255], 1);
    __syncthreads();
    int v = cnt[tid];
    int excl = block_excl_scan_256(v, tid, wsum);
    dbase[tid] = excl;
    __syncthreads();
    int n = b * 256 + tid;
    if (n < NN) indptr[n] = start + excl;
    cnt[tid] = 0;          // reuse as per-dst cursor
    __syncthreads();
    for (int i = start + tid; i < end; i += 256) {
        int dl = Adst[i] & 255;
        int r = atomicAdd(&cnt[dl], 1);
        int pos = start + dbase[dl] + r;
        edgedat[pos] = (unsigned long long)(unsigned int)Asrc[i] |
                       ((unsigned long long)__float_as_uint(Aea[i]) << 32);
    }
}

// ---------------- conv1 aggregation (no-max softmax) -> h1 as hi/lo bf16 ----------------
__global__ __launch_bounds__(256) void gat1_agg(
    const unsigned short* __restrict__ xs1b, const float* __restrict__ als,
    const float* __restrict__ ald, const unsigned long long* __restrict__ edgedat,
    const int* __restrict__ indptr, const float* __restrict__ consts,
    const float* __restrict__ b1, const float* __restrict__ g1,
    const float* __restrict__ be1,
    unsigned short* __restrict__ h1hi, unsigned short* __restrict__ h1lo) {
    __shared__ float exbuf[4][CAP1 * 4];
    __shared__ int srcbuf[4][CAP1];
    int wv = threadIdx.x >> 6;
    int lane = threadIdx.x & 63;
    int n = blockIdx.x * 4 + wv;
    int start = indptr[n];
    int deg = indptr[n + 1] - start;
    float ea_mean = consts[1];
    float ce[4] = {consts[2], consts[3], consts[4], consts[5]};
    float4 a4d = *(const float4*)(ald + (size_t)n * 4);
    float aldh[4] = {a4d.x, a4d.y, a4d.z, a4d.w};
    float4 a4s = *(const float4*)(als + (size_t)n * 4);
    float alsn[4] = {a4s.x, a4s.y, a4s.z, a4s.w};
    float ex0[4], sm[4];
    #pragma unroll
    for (int h = 0; h < 4; h++) {
        ex0[h] = __expf(lrelu(alsn[h] + aldh[h] + ea_mean * ce[h]));
        sm[h] = 0.f;
    }
    const unsigned long long* edp = edgedat + start;
    for (int i = lane; i < deg; i += 64) {
        int s; float eav;
        unpack_edge(edp[i], s, eav);
        float4 v4 = *(const float4*)(als + (size_t)s * 4);
        float alv[4] = {v4.x, v4.y, v4.z, v4.w};
        bool st = (i < CAP1);
        if (st) srcbuf[wv][i] = s * HC;
        #pragma unroll
        for (int h = 0; h < 4; h++) {
            float exv = __expf(lrelu(alv[h] + aldh[h] + eav * ce[h]));
            if (st) exbuf[wv][i * 4 + h] = exv;
            sm[h] += exv;
        }
    }
    #pragma unroll
    for (int h = 0; h < 4; h++)
        for (int off = 32; off > 0; off >>= 1) sm[h] += __shfl_xor(sm[h], off);
    float inv[4];
    #pragma unroll
    for (int h = 0; h < 4; h++) inv[h] = 1.0f / (sm[h] + ex0[h] + 1e-16f);
    int mcap = deg < CAP1 ? deg : CAP1;
    for (int i = lane; i < mcap; i += 64) {
        #pragma unroll
        for (int h = 0; h < 4; h++) exbuf[wv][i * 4 + h] *= inv[h];
    }
    int c = lane * 2;
    int h = lane >> 4;
    float wsl = ex0[h] * inv[h];
    float2 vself = bf2f2(*(const unsigned int*)(xs1b + (size_t)n * HC + c));
    float accx = vself.x * wsl, accy = vself.y * wsl;
    int i = 0;
    for (; i + 4 <= mcap; i += 4) {
        float w0 = exbuf[wv][(i + 0) * 4 + h];
        float w1 = exbuf[wv][(i + 1) * 4 + h];
        float w2 = exbuf[wv][(i + 2) * 4 + h];
        float w3 = exbuf[wv][(i + 3) * 4 + h];
        int o0 = srcbuf[wv][i + 0], o1 = srcbuf[wv][i + 1];
        int o2 = srcbuf[wv][i + 2], o3 = srcbuf[wv][i + 3];
        float2 v0 = bf2f2(*(const unsigned int*)(xs1b + o0 + c));
        float2 v1 = bf2f2(*(const unsigned int*)(xs1b + o1 + c));
        float2 v2 = bf2f2(*(const unsigned int*)(xs1b + o2 + c));
        float2 v3 = bf2f2(*(const unsigned int*)(xs1b + o3 + c));
        accx += v0.x * w0; accy += v0.y * w0;
        accx += v1.x * w1; accy += v1.y * w1;
        accx += v2.x * w2; accy += v2.y * w2;
        accx += v3.x * w3; accy += v3.y * w3;
    }
    for (; i < mcap; i++) {
        float w0 = exbuf[wv][i * 4 + h];
        int o0 = srcbuf[wv][i];
        float2 v0 = bf2f2(*(const unsigned int*)(xs1b + o0 + c));
        accx += v0.x * w0; accy += v0.y * w0;
    }
    for (; i < deg; i++) {  // spill fallback (deg > CAP1): recompute
        int s; float eav;
        unpack_edge(edp[i], s, eav);
        float a = lrelu(als[(size_t)s * 4 + h] + aldh[h] + eav * ce[h]);
        float w0 = __expf(a) * inv[h];
        float2 v0 = bf2f2(*(const unsigned int*)(xs1b + (size_t)s * HC + c));
        accx += v0.x * w0; accy += v0.y * w0;
    }
    float o0 = accx + b1[c];
    float o1 = accy + b1[c + 1];
    o0 = o0 * (g1[c] * BN_RS) + be1[c];
    o1 = o1 * (g1[c + 1] * BN_RS) + be1[c + 1];
    o0 = elu(o0);
    o1 = elu(o1);
    // split hi/lo bf16 for the MFMA gemm2
    unsigned short h0 = f2bf(o0), h1v = f2bf(o1);
    unsigned short l0 = f2bf(o0 - bf2f(h0)), l1 = f2bf(o1 - bf2f(h1v));
    *(unsigned int*)(h1hi + (size_t)n * HC + c) = (unsigned int)h0 | ((unsigned int)h1v << 16);
    *(unsigned int*)(h1lo + (size_t)n * HC + c) = (unsigned int)l0 | ((unsigned int)l1 << 16);
}

// ---------------- gemm2 via MFMA split-bf16 + fused al2 ----------------
__global__ __launch_bounds__(256) void gemm2_mfma(const unsigned short* __restrict__ h1hi,
                                                  const unsigned short* __restrict__ h1lo,
                                                  const unsigned short* __restrict__ W2hi,
                                                  const unsigned short* __restrict__ W2lo,
                                                  const float* __restrict__ as2,
                                                  const float* __restrict__ ad2,
                                                  unsigned short* __restrict__ xs2b,
                                                  float* __restrict__ als2,
                                                  float* __restrict__ ald2) {
    int tid = threadIdx.x;
    int lane = tid & 63, wv = tid >> 6;
    int row0 = blockIdx.x * 64 + wv * 16;
    if (row0 >= NN) return;
    int m = lane & 15, q = lane >> 4;
    f32x4 acc[2];
    acc[0] = {0.f, 0.f, 0.f, 0.f};
    acc[1] = {0.f, 0.f, 0.f, 0.f};
    const unsigned short* rhi = h1hi + (size_t)(row0 + m) * HC + q * 8;
    const unsigned short* rlo = h1lo + (size_t)(row0 + m) * HC + q * 8;
    #pragma unroll
    for (int kt = 0; kt < 4; kt++) {
        short8 ahi = *(const short8*)(rhi + kt * 32);
        short8 alo = *(const short8*)(rlo + kt * 32);
        #pragma unroll
        for (int nt = 0; nt < 2; nt++) {
            size_t fb = ((size_t)(nt * 4 + kt) * 64 + lane) * 8;
            short8 bhi = *(const short8*)(W2hi + fb);
            short8 blo = *(const short8*)(W2lo + fb);
            acc[nt] = __builtin_amdgcn_mfma_f32_16x16x32_bf16(ahi, bhi, acc[nt], 0, 0, 0);
            acc[nt] = __builtin_amdgcn_mfma_f32_16x16x32_bf16(ahi, blo, acc[nt], 0, 0, 0);
            acc[nt] = __builtin_amdgcn_mfma_f32_16x16x32_bf16(alo, bhi, acc[nt], 0, 0, 0);
        }
    }
    float a0 = as2[m], a1 = as2[m + 16];
    float d0 = ad2[m], d1 = ad2[m + 16];
    #pragma unroll
    for (int reg = 0; reg < 4; reg++) {
        int row = row0 + q * 4 + reg;
        xs2b[(size_t)row * CD + m]      = f2bf(acc[0][reg]);
        xs2b[(size_t)row * CD + 16 + m] = f2bf(acc[1][reg]);
        float s = acc[0][reg] * a0 + acc[1][reg] * a1;
        float d = acc[0][reg] * d0 + acc[1][reg] * d1;
        #pragma unroll
        for (int off = 1; off < 16; off <<= 1) {
            s += __shfl_xor(s, off);
            d += __shfl_xor(d, off);
        }
        if (m == 0) { als2[row] = s; ald2[row] = d; }
    }
}

// ---------------- conv2 aggregation + fused MLP heads (no-max softmax) ----------------
__global__ __launch_bounds__(256) void gat2_agg(
    const unsigned short* __restrict__ xs2b, const float* __restrict__ als,
    const float* __restrict__ ald, const unsigned long long* __restrict__ edgedat,
    const int* __restrict__ indptr, const float* __restrict__ consts,
    const float* __restrict__ b2, const float* __restrict__ g2, const float* __restrict__ be2,
    const float* __restrict__ Wc1, const float* __restrict__ bc1,
    const float* __restrict__ Wc2, const float* __restrict__ bc2,
    const float* __restrict__ Wr1, const float* __restrict__ br1,
    const float* __restrict__ Wr2, const float* __restrict__ br2,
    float* __restrict__ hout, float* __restrict__ cls, float* __restrict__ reg) {
    __shared__ float exbuf[4][CAP2];
    __shared__ int srcbuf[4][CAP2];
    __shared__ float hbuf[4][32];
    int wv = threadIdx.x >> 6;
    int lane = threadIdx.x & 63;
    int n = blockIdx.x * 4 + wv;
    int start = indptr[n];
    int deg = indptr[n + 1] - start;
    float ea_mean = consts[1];
    float ce = consts[6];
    float aldn = ald[n];
    float ex0 = __expf(lrelu(als[n] + aldn + ea_mean * ce));
    float sm = 0.f;
    const unsigned long long* edp = edgedat + start;
    for (int i = lane; i < deg; i += 64) {
        int s; float eav;
        unpack_edge(edp[i], s, eav);
        float exv = __expf(lrelu(als[s] + aldn + eav * ce));
        if (i < CAP2) { srcbuf[wv][i] = s * CD; exbuf[wv][i] = exv; }
        sm += exv;
    }
    for (int off = 32; off > 0; off >>= 1) sm += __shfl_xor(sm, off);
    float invd = 1.0f / (sm + ex0 + 1e-16f);
    int mcap = deg < CAP2 ? deg : CAP2;
    for (int i = lane; i < mcap; i += 64) exbuf[wv][i] *= invd;
    int quarter = lane >> 4;
    int cl = lane & 15;
    int c = cl * 2;
    float accx = 0.f, accy = 0.f;
    if (quarter == 0) {
        float2 vs = bf2f2(*(const unsigned int*)(xs2b + (size_t)n * CD + c));
        float wsl = ex0 * invd;
        accx = vs.x * wsl; accy = vs.y * wsl;
    }
    for (int i = quarter; i < mcap; i += 4) {
        float w0 = exbuf[wv][i];
        int o0 = srcbuf[wv][i];
        float2 v0 = bf2f2(*(const unsigned int*)(xs2b + o0 + c));
        accx += v0.x * w0; accy += v0.y * w0;
    }
    for (int i = CAP2 + quarter; i < deg; i += 4) {  // spill fallback
        int s; float eav;
        unpack_edge(edp[i], s, eav);
        float w0 = __expf(lrelu(als[s] + aldn + eav * ce)) * invd;
        float2 v0 = bf2f2(*(const unsigned int*)(xs2b + (size_t)s * CD + c));
        accx += v0.x * w0; accy += v0.y * w0;
    }
    accx += __shfl_xor(accx, 16); accy += __shfl_xor(accy, 16);
    accx += __shfl_xor(accx, 32); accy += __shfl_xor(accy, 32);
    if (lane < 16) {
        float o0 = accx + b2[c];
        float o1 = accy + b2[c + 1];
        o0 = o0 * (g2[c] * BN_RS) + be2[c];
        o1 = o1 * (g2[c + 1] * BN_RS) + be2[c + 1];
        o0 = elu(o0);
        o1 = elu(o1);
        hbuf[wv][c] = o0;
        hbuf[wv][c + 1] = o1;
        *(float2*)(hout + (size_t)n * CD + c) = make_float2(o0, o1);
    }
    __syncthreads();
    float r0 = 0.f, r1 = 0.f;
    if (lane < 32) {
        int j = lane & 15;
        bool iscls = lane < 16;
        float s = iscls ? bc1[j] : br1[j];
        #pragma unroll
        for (int cc = 0; cc < 32; cc++) {
            float w = iscls ? Wc1[cc * 16 + j] : Wr1[cc * 16 + j];
            s += hbuf[wv][cc] * w;
        }
        s = fmaxf(s, 0.f);
        if (iscls) { r0 = s * Wc2[j * 2]; r1 = s * Wc2[j * 2 + 1]; }
        else       { r0 = s * Wr2[j]; }
    }
    #pragma unroll
    for (int off = 1; off < 16; off <<= 1) {
        r0 += __shfl_xor(r0, off);
        r1 += __shfl_xor(r1, off);
    }
    if (lane == 0)  *(float2*)(cls + (size_t)n * 2) = make_float2(r0 + bc2[0], r1 + bc2[1]);
    if (lane == 16) reg[n] = r0 + br2[0];
}

// ---------------- launch ----------------
extern "C" void kernel_launch(void* const* d_in, const int* in_sizes, int n_in,
                              void* d_out, int out_size, void* d_ws, size_t ws_size,
                              hipStream_t stream) {
    const float* x   = (const float*)d_in[0];
    const int*   ei  = (const int*)d_in[1];
    const float* ea  = (const float*)d_in[2];
    const float* W1  = (const float*)d_in[3];
    const float* as1 = (const float*)d_in[4];
    const float* ad1 = (const float*)d_in[5];
    const float* We1 = (const float*)d_in[6];
    const float* ae1 = (const float*)d_in[7];
    const float* b1  = (const float*)d_in[8];
    const float* g1  = (const float*)d_in[9];
    const float* be1 = (const float*)d_in[10];
    const float* W2  = (const float*)d_in[11];
    const float* as2 = (const float*)d_in[12];
    const float* ad2 = (const float*)d_in[13];
    const float* We2 = (const float*)d_in[14];
    const float* ae2 = (const float*)d_in[15];
    const float* b2  = (const float*)d_in[16];
    const float* g2  = (const float*)d_in[17];
    const float* be2 = (const float*)d_in[18];
    const float* Wc1 = (const float*)d_in[19];
    const float* bc1 = (const float*)d_in[20];
    const float* Wc2 = (const float*)d_in[21];
    const float* bc2 = (const float*)d_in[22];
    const float* Wr1 = (const float*)d_in[23];
    const float* br1 = (const float*)d_in[24];
    const float* Wr2 = (const float*)d_in[25];
    const float* br2 = (const float*)d_in[26];

    char* ws = (char*)d_ws;
    unsigned short* xs1b = (unsigned short*)(ws + 0);          // N*128 bf16 = 12.8 MB
    unsigned short* h1hi = (unsigned short*)(ws + 12800000);   // N*128 bf16 = 12.8 MB
    unsigned short* h1lo = (unsigned short*)(ws + 25600000);   // N*128 bf16 = 12.8 MB
    // staging arrays alias h1hi/h1lo (consumed by stage2 before gat1 writes them)
    int*   Adst          = (int*)(ws + 12800000);              // E = 6.4 MB
    int*   Asrc          = (int*)(ws + 19200000);              // E = 6.4 MB
    float* Aea           = (float*)(ws + 25600000);            // E = 6.4 MB (ends 32.0 MB)
    unsigned short* xs2b = (unsigned short*)(ws + 38400000);   // N*32 bf16 = 3.2 MB
    float* als1          = (float*)(ws + 41600000);            // N*4
    float* ald1          = (float*)(ws + 42400000);            // N*4
    float* als2          = (float*)(ws + 43200000);            // N
    float* ald2          = (float*)(ws + 43400000);            // N
    float* consts        = (float*)(ws + 43600000);            // 8 floats
    int*   bucketHist    = (int*)(ws + 43600128);              // 196
    int*   bucketBase    = (int*)(ws + 43601024);              // 197
    int*   bucketCursor  = (int*)(ws + 43601920);              // 196
    int*   indptr        = (int*)(ws + 43602816);              // N+1
    unsigned long long* edgedat = (unsigned long long*)(ws + 43802824);  // E*8 -> ends 56602824
    unsigned short* W1hi = (unsigned short*)(ws + 56602832);   // 64 KB
    unsigned short* W1lo = (unsigned short*)(ws + 56668368);   // 64 KB
    unsigned short* W2hi = (unsigned short*)(ws + 56733904);   // 8 KB
    unsigned short* W2lo = (unsigned short*)(ws + 56742096);   // 8 KB (ends ~56.75 MB)

    float* out_cls = (float*)d_out;            // [N,2]
    float* out_reg = out_cls + 2 * NN;         // [N]
    float* out_h   = out_cls + 3 * NN;         // [N,32]

    hipMemsetAsync(bucketHist, 0, NBKT * sizeof(int), stream);
    hipMemsetAsync(consts, 0, 8 * sizeof(float), stream);

    // K0: weight prepacks + attention consts
    k0_prep<<<19, 256, 0, stream>>>(W1, W2, We1, ae1, We2, ae2,
                                    W1hi, W1lo, W2hi, W2lo, consts);
    // K_A: hist + gemm1 fused (independent paths overlap)
    kA_hist_gemm1<<<HIST_B + G1_B, 256, 0, stream>>>(ei, ea, x, W1hi, W1lo,
                                                     bucketHist, consts, xs1b);
    bucket_scan<<<1, 256, 0, stream>>>(bucketHist, bucketBase, bucketCursor, indptr, consts);
    // K_B: stage1 + al1 fused
    kB_stage1_al1<<<S1_B + 782, 256, 0, stream>>>(ei, ea, bucketCursor, Adst, Asrc, Aea,
                                                  xs1b, as1, ad1, als1, ald1);
    stage2_kernel<<<NBKT, 256, 0, stream>>>(bucketBase, Adst, Asrc, Aea, indptr, edgedat);

    // conv1 aggregation (writes h1 as hi/lo bf16)
    gat1_agg<<<NN / 4, 256, 0, stream>>>(xs1b, als1, ald1, edgedat, indptr, consts,
                                         b1, g1, be1, h1hi, h1lo);
    // conv2: MFMA gemm2 + fused al2
    gemm2_mfma<<<G1_B, 256, 0, stream>>>(h1hi, h1lo, W2hi, W2lo, as2, ad2,
                                         xs2b, als2, ald2);
    gat2_agg<<<NN / 4, 256, 0, stream>>>(xs2b, als2, ald2, edgedat, indptr, consts,
                                         b2, g2, be2, Wc1, bc1, Wc2, bc2,
                                         Wr1, br1, Wr2, br2, out_h, out_cls, out_reg);
}